// Round 1
// 911.222 us; speedup vs baseline: 1.1311x; 1.1311x over previous
//
#include <hip/hip_runtime.h>

#define NB 4
#define NS 2048
#define ND 2048
#define NH 16
#define NHD 128

typedef __bf16 bf16;
typedef __attribute__((ext_vector_type(8))) __bf16 bf16x8;
typedef __attribute__((ext_vector_type(4))) __bf16 bf16x4;
typedef __attribute__((ext_vector_type(4))) float f32x4;

#define MFMA(a, b, c) __builtin_amdgcn_mfma_f32_16x16x32_bf16(a, b, c, 0, 0, 0)

// async global->LDS, 16 B per lane. LDS dest = wave-uniform base + lane*16.
__device__ __forceinline__ void gload16(const bf16* g, bf16* l) {
    __builtin_amdgcn_global_load_lds(
        (const __attribute__((address_space(1))) void*)g,
        (__attribute__((address_space(3))) void*)l, 16, 0, 0);
}

// ---------------------------------------------------------------------------
// Kernel 0: fp32 -> bf16 convert, 8 elems/thread, exact grid (n % 2048 == 0)
// ---------------------------------------------------------------------------
__global__ __launch_bounds__(256) void cvt_bf16(const float* __restrict__ src,
                                                bf16* __restrict__ dst)
{
    size_t i = ((size_t)blockIdx.x * 256 + threadIdx.x) * 8;
    float4 a = *reinterpret_cast<const float4*>(src + i);
    float4 b = *reinterpret_cast<const float4*>(src + i + 4);
    bf16x8 o;
    o[0] = (bf16)a.x; o[1] = (bf16)a.y; o[2] = (bf16)a.z; o[3] = (bf16)a.w;
    o[4] = (bf16)b.x; o[5] = (bf16)b.y; o[6] = (bf16)b.z; o[7] = (bf16)b.w;
    *reinterpret_cast<bf16x8*>(dst + i) = o;
}

// ---------------------------------------------------------------------------
// Kernel 1: fused QKV projection + bias + per-head RMSNorm (Q,K) bf16 out
// (B,H,S,Hd); V written TRANSPOSED (B,H,Hd,S). bf16 inputs, m97-style
// global_load_lds staging (unpadded LDS, 16B/lane), 128x128 tile, BK=64.
// ---------------------------------------------------------------------------
__global__ __launch_bounds__(256) void qkv_gemm(
    const bf16* __restrict__ Xb, const bf16* __restrict__ Wb,
    const float* __restrict__ bq, const float* __restrict__ bk, const float* __restrict__ bv,
    const float* __restrict__ qw, const float* __restrict__ kw,
    bf16* __restrict__ Oq, bf16* __restrict__ Ok, bf16* __restrict__ Ov)
{
    const int mat = blockIdx.z;
    const bf16* X     = Xb + (size_t)mat * (size_t)NB * NS * ND;
    const bf16* W     = Wb + (size_t)mat * ND * ND;
    const float* bias = (mat == 0) ? bq : (mat == 1) ? bk : bv;
    const float* nw   = (mat == 0) ? qw : kw;
    bf16* Out         = (mat == 0) ? Oq : (mat == 1) ? Ok : Ov;

    // pool: As[128*64] | Bs[128*64] bf16 during k-loop (32 KB, unpadded for
    // global_load_lds); aliased by Ts[128][136] (34816 B) in the V epilogue.
    __shared__ alignas(16) char pool[34816];
    __shared__ float red[128][2];
    __shared__ float scl[128];
    bf16* As = (bf16*)pool;
    bf16* Bs = (bf16*)(pool + 16384);

    const int tid  = threadIdx.x;
    const int lane = tid & 63;
    const int w    = tid >> 6;
    const int wm   = w & 1, wn = w >> 1;
    const int quad = lane >> 4, l15 = lane & 15;
    const int m0   = blockIdx.y * 128;
    const int n0   = blockIdx.x * 128;   // head index == blockIdx.x

    const int rsub = lane >> 3;          // 0..7
    const int csub = (lane & 7) * 8;     // 0..56

    f32x4 acc[4][4] = {};

    for (int k0 = 0; k0 < ND; k0 += 64) {
        const bf16* Ag = X + (size_t)m0 * ND + k0;
        const bf16* Bg = W + (size_t)n0 * ND + k0;
        #pragma unroll
        for (int i = 0; i < 4; ++i) {
            int idx = w * 4 + i;         // 16 chunks of 8 rows x 64 cols
            gload16(Ag + (size_t)(idx * 8 + rsub) * ND + csub, As + idx * 512);
            gload16(Bg + (size_t)(idx * 8 + rsub) * ND + csub, Bs + idx * 512);
        }
        __syncthreads();
        #pragma unroll
        for (int ks = 0; ks < 2; ++ks) {
            const int kb = ks * 32 + quad * 8;
            bf16x8 af[4], bfr[4];
            #pragma unroll
            for (int mi = 0; mi < 4; ++mi)
                af[mi] = *reinterpret_cast<const bf16x8*>(As + (wm * 64 + mi * 16 + l15) * 64 + kb);
            #pragma unroll
            for (int ni = 0; ni < 4; ++ni)
                bfr[ni] = *reinterpret_cast<const bf16x8*>(Bs + (wn * 64 + ni * 16 + l15) * 64 + kb);
            #pragma unroll
            for (int mi = 0; mi < 4; ++mi)
                #pragma unroll
                for (int ni = 0; ni < 4; ++ni)
                    acc[mi][ni] = MFMA(af[mi], bfr[ni], acc[mi][ni]);
        }
        __syncthreads();
    }

    // epilogue: bias
    #pragma unroll
    for (int ni = 0; ni < 4; ++ni) {
        float bn = bias[n0 + wn * 64 + ni * 16 + l15];
        #pragma unroll
        for (int mi = 0; mi < 4; ++mi)
            #pragma unroll
            for (int r = 0; r < 4; ++r)
                acc[mi][ni][r] += bn;
    }

    const int hh = blockIdx.x;

    if (mat == 2) {
        // ---- V path: transpose tile in LDS, write (B,H,Hd,S) coalesced ----
        bf16 (*Ts)[136] = (bf16(*)[136])pool;
        #pragma unroll
        for (int mi = 0; mi < 4; ++mi)
            #pragma unroll
            for (int ni = 0; ni < 4; ++ni) {
                bf16x4 t;
                #pragma unroll
                for (int r = 0; r < 4; ++r) t[r] = (bf16)acc[mi][ni][r];
                *reinterpret_cast<bf16x4*>(
                    &Ts[wn * 64 + ni * 16 + l15][wm * 64 + mi * 16 + quad * 4]) = t;
            }
        __syncthreads();
        const int bb = m0 >> 11;               // 128-row tile is within one batch
        const int s0 = m0 & (NS - 1);
        const size_t obase = ((size_t)bb * NH + hh) * (size_t)NHD * NS;
        #pragma unroll
        for (int i = 0; i < 8; ++i) {
            int d = i * 16 + (tid >> 4);
            int c = (tid & 15) * 8;
            *reinterpret_cast<bf16x8*>(Out + obase + (size_t)d * NS + s0 + c) =
                *reinterpret_cast<const bf16x8*>(&Ts[d][c]);
        }
        return;
    }

    // ---- Q/K path: per-head RMSNorm over the 128 cols, write (B,H,S,Hd) ----
    #pragma unroll
    for (int mi = 0; mi < 4; ++mi) {
        float ss[4];
        #pragma unroll
        for (int r = 0; r < 4; ++r) {
            float s = 0.f;
            #pragma unroll
            for (int ni = 0; ni < 4; ++ni) { float v = acc[mi][ni][r]; s += v * v; }
            ss[r] = s;
        }
        #pragma unroll
        for (int off = 1; off < 16; off <<= 1)
            #pragma unroll
            for (int r = 0; r < 4; ++r)
                ss[r] += __shfl_xor(ss[r], off);
        if (l15 == 0) {
            #pragma unroll
            for (int r = 0; r < 4; ++r)
                red[wm * 64 + mi * 16 + quad * 4 + r][wn] = ss[r];
        }
    }
    __syncthreads();
    if (tid < 128)
        scl[tid] = rsqrtf((red[tid][0] + red[tid][1]) * (1.0f / 128.0f) + 1e-6f);
    __syncthreads();

    #pragma unroll
    for (int mi = 0; mi < 4; ++mi) {
        #pragma unroll
        for (int r = 0; r < 4; ++r) {
            int row = wm * 64 + mi * 16 + quad * 4 + r;
            int mg  = m0 + row;
            int bb  = mg >> 11;            // token -> batch (S = 2048)
            int ssi = mg & (NS - 1);
            size_t base = (((size_t)bb * NH + hh) * NS + ssi) * NHD;
            float sc_r = scl[row];
            #pragma unroll
            for (int ni = 0; ni < 4; ++ni) {
                int col = wn * 64 + ni * 16 + l15;   // == d within head
                float v = acc[mi][ni][r] * sc_r * nw[col];
                Out[base + col] = (bf16)v;
            }
        }
    }
}

// ---------------------------------------------------------------------------
// Kernel 2: flash attention. One block per (b, h, 64-row q tile). 4 waves,
// each wave owns 16 q rows. K tiles of 64 keys; V comes in TRANSPOSED
// (b,h,d,s). Swapped QK^T (mfma(K,Q)) puts a full q-row per lane -> softmax
// is in-register (tree + 2 shfl_xor). P round-trips LDS as 4 ds_write_b64.
// K/V staging is register-split: global loads issued right after QK^T,
// LDS writes after the PV barrier (T14). Defer-max skips O rescale when the
// running max doesn't grow (T13). setprio(1) around MFMA clusters (T5).
// ---------------------------------------------------------------------------
__global__ __launch_bounds__(256, 4) void flash_attn(
    const bf16* __restrict__ Q, const bf16* __restrict__ K, const bf16* __restrict__ Vt,
    bf16* __restrict__ O)
{
    __shared__ alignas(16) char pool[17408];      // Ks[64][136] | Ps[64][72] alias
    __shared__ bf16 VtS[128][72];                 // d-major V tile
    bf16 (*Ks)[136] = (bf16(*)[136])pool;
    bf16 (*Ps)[72]  = (bf16(*)[72])pool;

    const int tid  = threadIdx.x;
    const int lane = tid & 63;
    const int w    = tid >> 6;
    const int quad = lane >> 4, l15 = lane & 15;
    const int b    = blockIdx.z, h = blockIdx.y;
    const int q0   = blockIdx.x * 64;
    const size_t hb = ((size_t)b * NH + h) * (size_t)NS * NHD;
    const bf16* Qh  = Q + hb;
    const bf16* Kh  = K + hb;
    const bf16* Vth = Vt + hb;    // (b,h,d,s)

    // Q fragments in registers (B-operand for swapped QK^T): col = l15 = q row
    bf16x8 qf[4];
    #pragma unroll
    for (int ks = 0; ks < 4; ++ks)
        qf[ks] = *reinterpret_cast<const bf16x8*>(
            Qh + (size_t)(q0 + w * 16 + l15) * NHD + ks * 32 + quad * 8);

    // staging coordinates (same layout as before, now via registers)
    const int kr = tid >> 4, kc = (tid & 15) * 8;      // K: 64 rows x 128 d
    const int vr = tid >> 3, vc = (tid & 7) * 8;       // Vt: 128 d x 64 keys
    const bf16* kp = Kh + (size_t)kr * NHD + kc;       // advances 64*NHD / tile
    const bf16* vp = Vth + (size_t)vr * NS + vc;       // advances 64 / tile

    f32x4 o[8] = {};
    float m_r = -1e30f, l_r = 0.f;
    const float C = 0.12751740f;   // (1/sqrt(128)) * log2(e) : fold scale into exp2

    // prologue: stage tile 0
    bf16x8 kreg[4], vreg[4];
    #pragma unroll
    for (int i = 0; i < 4; ++i)
        kreg[i] = *reinterpret_cast<const bf16x8*>(kp + (size_t)i * 16 * NHD);
    #pragma unroll
    for (int i = 0; i < 4; ++i)
        vreg[i] = *reinterpret_cast<const bf16x8*>(vp + (size_t)i * 32 * NS);
    #pragma unroll
    for (int i = 0; i < 4; ++i)
        *reinterpret_cast<bf16x8*>(&Ks[kr + i * 16][kc]) = kreg[i];
    #pragma unroll
    for (int i = 0; i < 4; ++i)
        *reinterpret_cast<bf16x8*>(&VtS[vr + i * 32][vc]) = vreg[i];
    __syncthreads();

    for (int kt = 0; kt < NS / 64; ++kt) {
        // S^T = K Q^T : D[key][q], lane holds keys {kb*16+quad*4+r}, q = l15
        f32x4 sacc[4] = {};
        __builtin_amdgcn_s_setprio(1);
        #pragma unroll
        for (int ks = 0; ks < 4; ++ks) {
            #pragma unroll
            for (int kb = 0; kb < 4; ++kb) {
                bf16x8 kf = *reinterpret_cast<const bf16x8*>(&Ks[kb * 16 + l15][ks * 32 + quad * 8]);
                sacc[kb] = MFMA(kf, qf[ks], sacc[kb]);
            }
        }
        __builtin_amdgcn_s_setprio(0);

        // issue next-tile global loads now; LDS writes happen after sync B
        if (kt + 1 < NS / 64) {
            kp += (size_t)64 * NHD;
            vp += 64;
            #pragma unroll
            for (int i = 0; i < 4; ++i)
                kreg[i] = *reinterpret_cast<const bf16x8*>(kp + (size_t)i * 16 * NHD);
            #pragma unroll
            for (int i = 0; i < 4; ++i)
                vreg[i] = *reinterpret_cast<const bf16x8*>(vp + (size_t)i * 32 * NS);
        }

        // ---- in-register online softmax (raw scores; scale folded into C) ----
        float t0 = fmaxf(fmaxf(sacc[0][0], sacc[0][1]), fmaxf(sacc[0][2], sacc[0][3]));
        float t1 = fmaxf(fmaxf(sacc[1][0], sacc[1][1]), fmaxf(sacc[1][2], sacc[1][3]));
        float t2 = fmaxf(fmaxf(sacc[2][0], sacc[2][1]), fmaxf(sacc[2][2], sacc[2][3]));
        float t3 = fmaxf(fmaxf(sacc[3][0], sacc[3][1]), fmaxf(sacc[3][2], sacc[3][3]));
        float mt = fmaxf(fmaxf(t0, t1), fmaxf(t2, t3));
        mt = fmaxf(mt, __shfl_xor(mt, 16));
        mt = fmaxf(mt, __shfl_xor(mt, 32));

        // defer-max: 64 raw ~= 5.7 scaled; p <= e^5.7, safe in bf16/fp32
        const bool grow = !__all(mt - m_r <= 64.0f);
        float alpha = 1.f;
        if (grow) {
            float mn = fmaxf(m_r, mt);
            alpha = __builtin_amdgcn_exp2f((m_r - mn) * C);
            m_r = mn;
        }
        const float mC = m_r * C;
        float rsk[4];
        #pragma unroll
        for (int kb = 0; kb < 4; ++kb) {
            #pragma unroll
            for (int r = 0; r < 4; ++r)
                sacc[kb][r] = __builtin_amdgcn_exp2f(sacc[kb][r] * C - mC);
            rsk[kb] = (sacc[kb][0] + sacc[kb][1]) + (sacc[kb][2] + sacc[kb][3]);
        }
        float rs = (rsk[0] + rsk[1]) + (rsk[2] + rsk[3]);
        rs += __shfl_xor(rs, 16);
        rs += __shfl_xor(rs, 32);
        l_r = l_r * alpha + rs;

        __syncthreads();   // A: all waves done reading Ks before Ps overwrites it

        // P -> Ps in A-operand layout [q][key]; rows are wave-private
        #pragma unroll
        for (int kb = 0; kb < 4; ++kb) {
            bf16x4 t;
            #pragma unroll
            for (int r = 0; r < 4; ++r) t[r] = (bf16)sacc[kb][r];
            *reinterpret_cast<bf16x4*>(&Ps[w * 16 + l15][kb * 16 + quad * 4]) = t;
        }

        if (grow) {   // wave-uniform branch
            float alr[4];
            #pragma unroll
            for (int r = 0; r < 4; ++r) alr[r] = __shfl(alpha, quad * 4 + r);
            #pragma unroll
            for (int ci = 0; ci < 8; ++ci)
                #pragma unroll
                for (int r = 0; r < 4; ++r) o[ci][r] *= alr[r];
        }

        // O += P @ V : lgkmcnt covers same-wave Ps write->read
        __builtin_amdgcn_s_setprio(1);
        #pragma unroll
        for (int ks = 0; ks < 2; ++ks) {
            bf16x8 a = *reinterpret_cast<const bf16x8*>(&Ps[w * 16 + l15][ks * 32 + quad * 8]);
            #pragma unroll
            for (int ci = 0; ci < 8; ++ci) {
                bf16x8 bb = *reinterpret_cast<const bf16x8*>(&VtS[ci * 16 + l15][ks * 32 + quad * 8]);
                o[ci] = MFMA(a, bb, o[ci]);
            }
        }
        __builtin_amdgcn_s_setprio(0);

        __syncthreads();   // B: Ps/VtS reads complete before restaging

        if (kt + 1 < NS / 64) {
            #pragma unroll
            for (int i = 0; i < 4; ++i)
                *reinterpret_cast<bf16x8*>(&Ks[kr + i * 16][kc]) = kreg[i];
            #pragma unroll
            for (int i = 0; i < 4; ++i)
                *reinterpret_cast<bf16x8*>(&VtS[vr + i * 32][vc]) = vreg[i];
            __syncthreads();   // C: next tile ready
        }
    }

    // epilogue: O /= l (l for row quad*4+r lives in lane (quad=0, l15=row))
    float lr_o[4];
    #pragma unroll
    for (int r = 0; r < 4; ++r) lr_o[r] = __shfl(l_r, quad * 4 + r);
    #pragma unroll
    for (int r = 0; r < 4; ++r) {
        int sg = q0 + w * 16 + quad * 4 + r;
        float inv = 1.0f / lr_o[r];
        size_t base = ((size_t)b * NS + sg) * ND + (size_t)h * NHD;
        #pragma unroll
        for (int ci = 0; ci < 8; ++ci)
            O[base + ci * 16 + l15] = (bf16)(o[ci][r] * inv);
    }
}

// ---------------------------------------------------------------------------
// Kernel 3: output projection. out[M][N] = A[M][K](bf16) @ Wo[N][K]^T + bo,
// fp32 out. Same m97-style staging as qkv_gemm.
// ---------------------------------------------------------------------------
__global__ __launch_bounds__(256) void oproj_gemm(
    const bf16* __restrict__ A, const bf16* __restrict__ W,
    const float* __restrict__ bias, float* __restrict__ Out)
{
    __shared__ alignas(16) bf16 As[128 * 64];
    __shared__ alignas(16) bf16 Bs[128 * 64];

    const int tid  = threadIdx.x;
    const int lane = tid & 63;
    const int w    = tid >> 6;
    const int wm   = w & 1, wn = w >> 1;
    const int quad = lane >> 4, l15 = lane & 15;
    const int m0   = blockIdx.y * 128;
    const int n0   = blockIdx.x * 128;

    const int rsub = lane >> 3;
    const int csub = (lane & 7) * 8;

    f32x4 acc[4][4] = {};

    for (int k0 = 0; k0 < ND; k0 += 64) {
        const bf16* Ag = A + (size_t)m0 * ND + k0;
        const bf16* Bg = W + (size_t)n0 * ND + k0;
        #pragma unroll
        for (int i = 0; i < 4; ++i) {
            int idx = w * 4 + i;
            gload16(Ag + (size_t)(idx * 8 + rsub) * ND + csub, As + idx * 512);
            gload16(Bg + (size_t)(idx * 8 + rsub) * ND + csub, Bs + idx * 512);
        }
        __syncthreads();
        #pragma unroll
        for (int ks = 0; ks < 2; ++ks) {
            const int kb = ks * 32 + quad * 8;
            bf16x8 af[4], bfr[4];
            #pragma unroll
            for (int mi = 0; mi < 4; ++mi)
                af[mi] = *reinterpret_cast<const bf16x8*>(As + (wm * 64 + mi * 16 + l15) * 64 + kb);
            #pragma unroll
            for (int ni = 0; ni < 4; ++ni)
                bfr[ni] = *reinterpret_cast<const bf16x8*>(Bs + (wn * 64 + ni * 16 + l15) * 64 + kb);
            #pragma unroll
            for (int mi = 0; mi < 4; ++mi)
                #pragma unroll
                for (int ni = 0; ni < 4; ++ni)
                    acc[mi][ni] = MFMA(af[mi], bfr[ni], acc[mi][ni]);
        }
        __syncthreads();
    }

    #pragma unroll
    for (int ni = 0; ni < 4; ++ni) {
        int col = n0 + wn * 64 + ni * 16 + l15;
        float bn = bias[col];
        #pragma unroll
        for (int mi = 0; mi < 4; ++mi)
            #pragma unroll
            for (int r = 0; r < 4; ++r) {
                int mg = m0 + wm * 64 + mi * 16 + quad * 4 + r;
                Out[(size_t)mg * ND + col] = acc[mi][ni][r] + bn;
            }
    }
}

// ---------------------------------------------------------------------------
extern "C" void kernel_launch(void* const* d_in, const int* in_sizes, int n_in,
                              void* d_out, int out_size, void* d_ws, size_t ws_size,
                              hipStream_t stream)
{
    const float* q  = (const float*)d_in[0];
    const float* k  = (const float*)d_in[1];
    const float* v  = (const float*)d_in[2];
    const float* Wq = (const float*)d_in[3];
    const float* bq = (const float*)d_in[4];
    const float* Wk = (const float*)d_in[5];
    const float* bk = (const float*)d_in[6];
    const float* Wv = (const float*)d_in[7];
    const float* bv = (const float*)d_in[8];
    const float* Wo = (const float*)d_in[9];
    const float* bo = (const float*)d_in[10];
    const float* qw = (const float*)d_in[11];
    const float* kw = (const float*)d_in[12];
    float* out = (float*)d_out;

    const size_t nX = (size_t)NB * NS * ND;   // 16,777,216
    const size_t nW = (size_t)ND * ND;        //  4,194,304

    // ws layout (bf16): Xb[3*nX] | Wb[4*nW] | Qn[nX] | Kn[nX] | Vtp[nX]
    // Ob aliases Xb (Xb dead after qkv_gemm; Ob written by flash_attn).
    bf16* Xb  = (bf16*)d_ws;
    bf16* Wb  = Xb + 3 * nX;
    bf16* Qn  = Wb + 4 * nW;
    bf16* Kn  = Qn + nX;
    bf16* Vtp = Kn + nX;
    bf16* Ob  = Xb;
    // total: (6*nX + 4*nW) * 2 B ~= 235 MB

    cvt_bf16<<<8192, 256, 0, stream>>>(q,  Xb);
    cvt_bf16<<<8192, 256, 0, stream>>>(k,  Xb + nX);
    cvt_bf16<<<8192, 256, 0, stream>>>(v,  Xb + 2 * nX);
    cvt_bf16<<<2048, 256, 0, stream>>>(Wq, Wb);
    cvt_bf16<<<2048, 256, 0, stream>>>(Wk, Wb + nW);
    cvt_bf16<<<2048, 256, 0, stream>>>(Wv, Wb + 2 * nW);
    cvt_bf16<<<2048, 256, 0, stream>>>(Wo, Wb + 3 * nW);

    qkv_gemm<<<dim3(16, 64, 3), dim3(256), 0, stream>>>(
        Xb, Wb, bq, bk, bv, qw, kw, Qn, Kn, Vtp);
    flash_attn<<<dim3(32, 16, 4), dim3(256), 0, stream>>>(Qn, Kn, Vtp, Ob);
    oproj_gemm<<<dim3(16, 64), dim3(256), 0, stream>>>(Ob, Wb + 3 * nW, bo, out);
}

// Round 2
// 775.474 us; speedup vs baseline: 1.3291x; 1.1751x over previous
//
#include <hip/hip_runtime.h>

#define NB 4
#define NS 2048
#define ND 2048
#define NH 16
#define NHD 128

typedef __bf16 bf16;
typedef __attribute__((ext_vector_type(8))) __bf16 bf16x8;
typedef __attribute__((ext_vector_type(4))) __bf16 bf16x4;
typedef __attribute__((ext_vector_type(4))) float f32x4;

#define MFMA(a, b, c) __builtin_amdgcn_mfma_f32_16x16x32_bf16(a, b, c, 0, 0, 0)

// async global->LDS, 16 B per lane. LDS dest = wave-uniform base + lane*16.
__device__ __forceinline__ void gload16(const bf16* g, bf16* l) {
    __builtin_amdgcn_global_load_lds(
        (const __attribute__((address_space(1))) void*)g,
        (__attribute__((address_space(3))) void*)l, 16, 0, 0);
}

#define BAR() do { asm volatile("" ::: "memory"); __builtin_amdgcn_s_barrier(); \
                   asm volatile("" ::: "memory"); } while (0)
#define VMCNT4() asm volatile("s_waitcnt vmcnt(4)" ::: "memory")

// ---------------------------------------------------------------------------
// 256x256x64 8-phase GEMM machinery (plain-HIP port of the HK cdna4 schedule)
// LDS: 2 K-tile buffers x {A,B} x 2 halves of [128][64] bf16 = 128 KiB.
// Swizzle st_16x32: byte-bit5 ^= byte-bit9 (== row&4), applied as linear
// gload_lds dest + pre-swizzled global source col + swizzled ds_read.
// ---------------------------------------------------------------------------
enum { RA00 = 0, RA01 = 16384, RA10 = 32768, RA11 = 49152,
       RB00 = 65536, RB01 = 81920, RB10 = 98304, RB11 = 114688 };

// stage one 128x64 half-tile: 512 threads x 2 x 16 B. gcorner = &G[row0][k0].
__device__ __forceinline__ void stage_half(const bf16* gcorner, char* lds_region,
                                           int w, int lane, int scol) {
    const bf16* g = gcorner + (size_t)(w * 16 + (lane >> 3)) * ND + scol;
    gload16(g, (bf16*)(lds_region + w * 2048));
    gload16(g + (size_t)8 * ND, (bf16*)(lds_region + w * 2048 + 1024));
}

// A fragments: af[mi*2+kk] for 4 row-groups starting at mi0 (runtime 0 or 4).
__device__ __forceinline__ void lds_loadA(const char* pool, int region, int mi0,
                                          int l15, int quad, bf16x8 (&af)[8]) {
    const int flip = (l15 & 4) << 3;
    #pragma unroll
    for (int mi = 0; mi < 4; ++mi) {
        const int rb = region + ((mi0 + mi) * 16 + l15) * 128;
        #pragma unroll
        for (int kk = 0; kk < 2; ++kk)
            af[mi * 2 + kk] = *reinterpret_cast<const bf16x8*>(
                pool + rb + ((kk * 64 + quad * 16) ^ flip));
    }
}

// B fragments: bfr[(NI0+ni)*2+kk] (NI0 compile-time: register index stays static).
template <int NI0>
__device__ __forceinline__ void lds_loadB(const char* pool, int region, int wn1,
                                          int l15, int quad, bf16x8 (&bfr)[8]) {
    const int flip = (l15 & 4) << 3;
    #pragma unroll
    for (int ni = 0; ni < 2; ++ni) {
        const int rb = region + (wn1 * 64 + (NI0 + ni) * 16 + l15) * 128;
        #pragma unroll
        for (int kk = 0; kk < 2; ++kk)
            bfr[(NI0 + ni) * 2 + kk] = *reinterpret_cast<const bf16x8*>(
                pool + rb + ((kk * 64 + quad * 16) ^ flip));
    }
}

// one C-quadrant x K=64: 16 MFMA, wrapped in setprio (T5).
template <int MI0, int NI0>
__device__ __forceinline__ void mfma_quad(f32x4 (&acc)[8][4], const bf16x8 (&af)[8],
                                          const bf16x8 (&bfr)[8]) {
    __builtin_amdgcn_s_setprio(1);
    #pragma unroll
    for (int mi = 0; mi < 4; ++mi)
        #pragma unroll
        for (int ni = 0; ni < 2; ++ni)
            #pragma unroll
            for (int kk = 0; kk < 2; ++kk)
                acc[MI0 + mi][NI0 + ni] =
                    MFMA(af[mi * 2 + kk], bfr[(NI0 + ni) * 2 + kk], acc[MI0 + mi][NI0 + ni]);
    __builtin_amdgcn_s_setprio(0);
}

// the full 8-phase K-loop over 32 K-tiles (K=2048). Ab/Bb = &A[m0][0], &B[n0][0].
// Reads of tile 2i at P1-4 (buf0), 2i+1 at P5-8 (buf1); stages per the
// freed-region schedule; vmcnt(4) only at P4/P8. Tail prefetch overreads K
// into adjacent ws regions (allocated, never consumed).
#define GEMM256_KLOOP(Ab, Bb)                                                        \
    stage_half(Ab, pool + RA00, w, lane, scol);                                      \
    stage_half(Ab + (size_t)128 * ND, pool + RA01, w, lane, scol);                   \
    stage_half(Bb, pool + RB00, w, lane, scol);                                      \
    stage_half(Bb + (size_t)128 * ND, pool + RB01, w, lane, scol);                   \
    stage_half(Bb + 64, pool + RB10, w, lane, scol);                                 \
    stage_half(Bb + (size_t)128 * ND + 64, pool + RB11, w, lane, scol);              \
    VMCNT4();                                                                        \
    BAR();                                                                           \
    for (int i = 0; i < 16; ++i) {                                                   \
        const int kA = (2 * i + 1) * 64;                                             \
        const int kN = (2 * i + 2) * 64;                                             \
        const int kN3 = (2 * i + 3) * 64;                                            \
        /* P1 */                                                                     \
        lds_loadA(pool, rA0, 0, l15, quad, af);                                      \
        lds_loadB<0>(pool, rB0, wn1, l15, quad, bfr);                                \
        stage_half(Ab + kA, pool + RA10, w, lane, scol);                             \
        BAR(); mfma_quad<0, 0>(acc, af, bfr); BAR();                                 \
        /* P2 */                                                                     \
        lds_loadB<2>(pool, rB0, wn1, l15, quad, bfr);                                \
        stage_half(Ab + (size_t)128 * ND + kA, pool + RA11, w, lane, scol);          \
        BAR(); mfma_quad<0, 2>(acc, af, bfr); BAR();                                 \
        /* P3 */                                                                     \
        lds_loadA(pool, rA0, 4, l15, quad, af);                                      \
        stage_half(Bb + kN, pool + RB00, w, lane, scol);                             \
        BAR(); mfma_quad<4, 0>(acc, af, bfr); BAR();                                 \
        /* P4 */                                                                     \
        stage_half(Bb + (size_t)128 * ND + kN, pool + RB01, w, lane, scol);          \
        VMCNT4();                                                                    \
        BAR(); mfma_quad<4, 2>(acc, af, bfr); BAR();                                 \
        /* P5 */                                                                     \
        lds_loadA(pool, rA1, 0, l15, quad, af);                                      \
        lds_loadB<0>(pool, rB1, wn1, l15, quad, bfr);                                \
        stage_half(Ab + kN, pool + RA00, w, lane, scol);                             \
        BAR(); mfma_quad<0, 0>(acc, af, bfr); BAR();                                 \
        /* P6 */                                                                     \
        lds_loadB<2>(pool, rB1, wn1, l15, quad, bfr);                                \
        stage_half(Ab + (size_t)128 * ND + kN, pool + RA01, w, lane, scol);          \
        BAR(); mfma_quad<0, 2>(acc, af, bfr); BAR();                                 \
        /* P7 */                                                                     \
        lds_loadA(pool, rA1, 4, l15, quad, af);                                      \
        stage_half(Bb + kN3, pool + RB10, w, lane, scol);                            \
        BAR(); mfma_quad<4, 0>(acc, af, bfr); BAR();                                 \
        /* P8 */                                                                     \
        stage_half(Bb + (size_t)128 * ND + kN3, pool + RB11, w, lane, scol);         \
        VMCNT4();                                                                    \
        BAR(); mfma_quad<4, 2>(acc, af, bfr); BAR();                                 \
    }

// ---------------------------------------------------------------------------
// Kernel 0: fp32 -> bf16 convert, 8 elems/thread, exact grid (n % 2048 == 0)
// ---------------------------------------------------------------------------
__global__ __launch_bounds__(256) void cvt_bf16(const float* __restrict__ src,
                                                bf16* __restrict__ dst)
{
    size_t i = ((size_t)blockIdx.x * 256 + threadIdx.x) * 8;
    float4 a = *reinterpret_cast<const float4*>(src + i);
    float4 b = *reinterpret_cast<const float4*>(src + i + 4);
    bf16x8 o;
    o[0] = (bf16)a.x; o[1] = (bf16)a.y; o[2] = (bf16)a.z; o[3] = (bf16)a.w;
    o[4] = (bf16)b.x; o[5] = (bf16)b.y; o[6] = (bf16)b.z; o[7] = (bf16)b.w;
    *reinterpret_cast<bf16x8*>(dst + i) = o;
}

// ---------------------------------------------------------------------------
// Kernel 1: fused QKV projection + bias + per-head RMSNorm (Q,K), V transposed.
// 256x256 tile, BK=64, 8 waves, 8-phase counted-vmcnt schedule.
// N-tile spans 2 heads (head = 128 cols).
// ---------------------------------------------------------------------------
__global__ __launch_bounds__(512, 2) void qkv_gemm(
    const bf16* __restrict__ Xb, const bf16* __restrict__ Wb,
    const float* __restrict__ bq, const float* __restrict__ bk, const float* __restrict__ bv,
    const float* __restrict__ qw, const float* __restrict__ kw,
    bf16* __restrict__ Oq, bf16* __restrict__ Ok, bf16* __restrict__ Ov)
{
    const int mat = blockIdx.z;
    const bf16* X     = Xb + (size_t)mat * (size_t)NB * NS * ND;
    const bf16* W     = Wb + (size_t)mat * ND * ND;
    const float* bias = (mat == 0) ? bq : (mat == 1) ? bk : bv;
    const float* nw   = (mat == 0) ? qw : kw;
    bf16* Out         = (mat == 0) ? Oq : (mat == 1) ? Ok : Ov;

    __shared__ alignas(1024) char pool[131072];
    __shared__ float red[256][4];
    __shared__ float scl[256][2];

    const int tid  = threadIdx.x;
    const int lane = tid & 63;
    const int w    = tid >> 6;          // 0..7
    const int wm   = w >> 2;            // 0..1  (M half)
    const int wn   = w & 3;             // 0..3  (N quarter)
    const int wn1  = wn & 1;
    const int quad = lane >> 4, l15 = lane & 15;

    const int m0 = blockIdx.y * 256;
    const int n0 = blockIdx.x * 256;

    const int scol = ((lane & 7) * 8) ^ ((lane & 32) ? 16 : 0);  // pre-swizzled src col

    const int rA0 = RA00 + wm * 16384;          // this wave's A half, buf0/1
    const int rA1 = RA10 + wm * 16384;
    const int rB0 = RB00 + (wn >> 1) * 16384;   // this wave's B half, buf0/1
    const int rB1 = RB10 + (wn >> 1) * 16384;

    const bf16* Ab = X + (size_t)m0 * ND;
    const bf16* Bb = W + (size_t)n0 * ND;

    f32x4 acc[8][4] = {};
    bf16x8 af[8], bfr[8];

    GEMM256_KLOOP(Ab, Bb)

    // epilogue: bias
    #pragma unroll
    for (int ni = 0; ni < 4; ++ni) {
        float bn = bias[n0 + wn * 64 + ni * 16 + l15];
        #pragma unroll
        for (int mi = 0; mi < 8; ++mi)
            #pragma unroll
            for (int r = 0; r < 4; ++r)
                acc[mi][ni][r] += bn;
    }

    if (mat == 2) {
        // ---- V path: per-head LDS transpose, write (B,H,Hd,S) coalesced ----
        bf16 (*Ts)[264] = (bf16(*)[264])pool;
        const int bb = m0 >> 11;               // 256-row tile within one batch
        const int s0 = m0 & (NS - 1);
        #pragma unroll
        for (int h2 = 0; h2 < 2; ++h2) {
            __syncthreads();                   // pool free (drains stage queue too)
            if ((wn >> 1) == h2) {
                #pragma unroll
                for (int mi = 0; mi < 8; ++mi)
                    #pragma unroll
                    for (int ni = 0; ni < 4; ++ni) {
                        bf16x4 t;
                        #pragma unroll
                        for (int r = 0; r < 4; ++r) t[r] = (bf16)acc[mi][ni][r];
                        *reinterpret_cast<bf16x4*>(
                            &Ts[wn1 * 64 + ni * 16 + l15][wm * 128 + mi * 16 + quad * 4]) = t;
                    }
            }
            __syncthreads();
            const size_t obase = ((size_t)bb * NH + (n0 >> 7) + h2) * (size_t)NHD * NS;
            #pragma unroll
            for (int it = 0; it < 8; ++it) {
                int d = it * 16 + (tid >> 5);
                int c = (tid & 31) * 8;
                *reinterpret_cast<bf16x8*>(Out + obase + (size_t)d * NS + s0 + c) =
                    *reinterpret_cast<const bf16x8*>(&Ts[d][c]);
            }
        }
        return;
    }

    // ---- Q/K path: per-head RMSNorm (128 cols per head, 2 heads per tile) ----
    #pragma unroll
    for (int mi = 0; mi < 8; ++mi) {
        float ss[4];
        #pragma unroll
        for (int r = 0; r < 4; ++r) {
            float s = 0.f;
            #pragma unroll
            for (int ni = 0; ni < 4; ++ni) { float v = acc[mi][ni][r]; s += v * v; }
            ss[r] = s;
        }
        #pragma unroll
        for (int off = 1; off < 16; off <<= 1)
            #pragma unroll
            for (int r = 0; r < 4; ++r)
                ss[r] += __shfl_xor(ss[r], off);
        if (l15 == 0) {
            #pragma unroll
            for (int r = 0; r < 4; ++r)
                red[wm * 128 + mi * 16 + quad * 4 + r][wn] = ss[r];
        }
    }
    __syncthreads();
    {
        int row = tid >> 1, h2 = tid & 1;
        scl[row][h2] = rsqrtf((red[row][2 * h2] + red[row][2 * h2 + 1]) * (1.0f / 128.0f) + 1e-6f);
    }
    __syncthreads();

    const int hh = (n0 >> 7) + (wn >> 1);
    #pragma unroll
    for (int mi = 0; mi < 8; ++mi) {
        #pragma unroll
        for (int r = 0; r < 4; ++r) {
            int row = wm * 128 + mi * 16 + quad * 4 + r;
            int mg  = m0 + row;
            int bb  = mg >> 11;
            int ssi = mg & (NS - 1);
            size_t base = (((size_t)bb * NH + hh) * NS + ssi) * NHD;
            float sc_r = scl[row][wn >> 1];
            #pragma unroll
            for (int ni = 0; ni < 4; ++ni) {
                int col = (wn * 64 + ni * 16 + l15) & 127;   // d within head
                Out[base + col] = (bf16)(acc[mi][ni][r] * sc_r * nw[col]);
            }
        }
    }
}

// ---------------------------------------------------------------------------
// Kernel 2: flash attention (unchanged from previous round).
// ---------------------------------------------------------------------------
__global__ __launch_bounds__(256, 4) void flash_attn(
    const bf16* __restrict__ Q, const bf16* __restrict__ K, const bf16* __restrict__ Vt,
    bf16* __restrict__ O)
{
    __shared__ alignas(16) char apool[17408];     // Ks[64][136] | Ps[64][72] alias
    __shared__ bf16 VtS[128][72];                 // d-major V tile
    bf16 (*Ks)[136] = (bf16(*)[136])apool;
    bf16 (*Ps)[72]  = (bf16(*)[72])apool;

    const int tid  = threadIdx.x;
    const int lane = tid & 63;
    const int w    = tid >> 6;
    const int quad = lane >> 4, l15 = lane & 15;
    const int b    = blockIdx.z, h = blockIdx.y;
    const int q0   = blockIdx.x * 64;
    const size_t hb = ((size_t)b * NH + h) * (size_t)NS * NHD;
    const bf16* Qh  = Q + hb;
    const bf16* Kh  = K + hb;
    const bf16* Vth = Vt + hb;    // (b,h,d,s)

    bf16x8 qf[4];
    #pragma unroll
    for (int ks = 0; ks < 4; ++ks)
        qf[ks] = *reinterpret_cast<const bf16x8*>(
            Qh + (size_t)(q0 + w * 16 + l15) * NHD + ks * 32 + quad * 8);

    const int kr = tid >> 4, kc = (tid & 15) * 8;
    const int vr = tid >> 3, vc = (tid & 7) * 8;
    const bf16* kp = Kh + (size_t)kr * NHD + kc;
    const bf16* vp = Vth + (size_t)vr * NS + vc;

    f32x4 o[8] = {};
    float m_r = -1e30f, l_r = 0.f;
    const float C = 0.12751740f;   // (1/sqrt(128)) * log2(e)

    bf16x8 kreg[4], vreg[4];
    #pragma unroll
    for (int i = 0; i < 4; ++i)
        kreg[i] = *reinterpret_cast<const bf16x8*>(kp + (size_t)i * 16 * NHD);
    #pragma unroll
    for (int i = 0; i < 4; ++i)
        vreg[i] = *reinterpret_cast<const bf16x8*>(vp + (size_t)i * 32 * NS);
    #pragma unroll
    for (int i = 0; i < 4; ++i)
        *reinterpret_cast<bf16x8*>(&Ks[kr + i * 16][kc]) = kreg[i];
    #pragma unroll
    for (int i = 0; i < 4; ++i)
        *reinterpret_cast<bf16x8*>(&VtS[vr + i * 32][vc]) = vreg[i];
    __syncthreads();

    for (int kt = 0; kt < NS / 64; ++kt) {
        f32x4 sacc[4] = {};
        __builtin_amdgcn_s_setprio(1);
        #pragma unroll
        for (int ks = 0; ks < 4; ++ks) {
            #pragma unroll
            for (int kb = 0; kb < 4; ++kb) {
                bf16x8 kf = *reinterpret_cast<const bf16x8*>(&Ks[kb * 16 + l15][ks * 32 + quad * 8]);
                sacc[kb] = MFMA(kf, qf[ks], sacc[kb]);
            }
        }
        __builtin_amdgcn_s_setprio(0);

        if (kt + 1 < NS / 64) {
            kp += (size_t)64 * NHD;
            vp += 64;
            #pragma unroll
            for (int i = 0; i < 4; ++i)
                kreg[i] = *reinterpret_cast<const bf16x8*>(kp + (size_t)i * 16 * NHD);
            #pragma unroll
            for (int i = 0; i < 4; ++i)
                vreg[i] = *reinterpret_cast<const bf16x8*>(vp + (size_t)i * 32 * NS);
        }

        float t0 = fmaxf(fmaxf(sacc[0][0], sacc[0][1]), fmaxf(sacc[0][2], sacc[0][3]));
        float t1 = fmaxf(fmaxf(sacc[1][0], sacc[1][1]), fmaxf(sacc[1][2], sacc[1][3]));
        float t2 = fmaxf(fmaxf(sacc[2][0], sacc[2][1]), fmaxf(sacc[2][2], sacc[2][3]));
        float t3 = fmaxf(fmaxf(sacc[3][0], sacc[3][1]), fmaxf(sacc[3][2], sacc[3][3]));
        float mt = fmaxf(fmaxf(t0, t1), fmaxf(t2, t3));
        mt = fmaxf(mt, __shfl_xor(mt, 16));
        mt = fmaxf(mt, __shfl_xor(mt, 32));

        const bool grow = !__all(mt - m_r <= 64.0f);
        float alpha = 1.f;
        if (grow) {
            float mn = fmaxf(m_r, mt);
            alpha = __builtin_amdgcn_exp2f((m_r - mn) * C);
            m_r = mn;
        }
        const float mC = m_r * C;
        float rsk[4];
        #pragma unroll
        for (int kb = 0; kb < 4; ++kb) {
            #pragma unroll
            for (int r = 0; r < 4; ++r)
                sacc[kb][r] = __builtin_amdgcn_exp2f(sacc[kb][r] * C - mC);
            rsk[kb] = (sacc[kb][0] + sacc[kb][1]) + (sacc[kb][2] + sacc[kb][3]);
        }
        float rs = (rsk[0] + rsk[1]) + (rsk[2] + rsk[3]);
        rs += __shfl_xor(rs, 16);
        rs += __shfl_xor(rs, 32);
        l_r = l_r * alpha + rs;

        __syncthreads();

        #pragma unroll
        for (int kb = 0; kb < 4; ++kb) {
            bf16x4 t;
            #pragma unroll
            for (int r = 0; r < 4; ++r) t[r] = (bf16)sacc[kb][r];
            *reinterpret_cast<bf16x4*>(&Ps[w * 16 + l15][kb * 16 + quad * 4]) = t;
        }

        if (grow) {
            float alr[4];
            #pragma unroll
            for (int r = 0; r < 4; ++r) alr[r] = __shfl(alpha, quad * 4 + r);
            #pragma unroll
            for (int ci = 0; ci < 8; ++ci)
                #pragma unroll
                for (int r = 0; r < 4; ++r) o[ci][r] *= alr[r];
        }

        __builtin_amdgcn_s_setprio(1);
        #pragma unroll
        for (int ks = 0; ks < 2; ++ks) {
            bf16x8 a = *reinterpret_cast<const bf16x8*>(&Ps[w * 16 + l15][ks * 32 + quad * 8]);
            #pragma unroll
            for (int ci = 0; ci < 8; ++ci) {
                bf16x8 bb = *reinterpret_cast<const bf16x8*>(&VtS[ci * 16 + l15][ks * 32 + quad * 8]);
                o[ci] = MFMA(a, bb, o[ci]);
            }
        }
        __builtin_amdgcn_s_setprio(0);

        __syncthreads();

        if (kt + 1 < NS / 64) {
            #pragma unroll
            for (int i = 0; i < 4; ++i)
                *reinterpret_cast<bf16x8*>(&Ks[kr + i * 16][kc]) = kreg[i];
            #pragma unroll
            for (int i = 0; i < 4; ++i)
                *reinterpret_cast<bf16x8*>(&VtS[vr + i * 32][vc]) = vreg[i];
            __syncthreads();
        }
    }

    float lr_o[4];
    #pragma unroll
    for (int r = 0; r < 4; ++r) lr_o[r] = __shfl(l_r, quad * 4 + r);
    #pragma unroll
    for (int r = 0; r < 4; ++r) {
        int sg = q0 + w * 16 + quad * 4 + r;
        float inv = 1.0f / lr_o[r];
        size_t base = ((size_t)b * NS + sg) * ND + (size_t)h * NHD;
        #pragma unroll
        for (int ci = 0; ci < 8; ++ci)
            O[base + ci * 16 + l15] = (bf16)(o[ci][r] * inv);
    }
}

// ---------------------------------------------------------------------------
// Kernel 3: output projection, 256x256 8-phase. fp32 out + bias.
// ---------------------------------------------------------------------------
__global__ __launch_bounds__(512, 2) void oproj_gemm(
    const bf16* __restrict__ A, const bf16* __restrict__ Wt,
    const float* __restrict__ bias, float* __restrict__ Out)
{
    __shared__ alignas(1024) char pool[131072];

    const int tid  = threadIdx.x;
    const int lane = tid & 63;
    const int w    = tid >> 6;
    const int wm   = w >> 2;
    const int wn   = w & 3;
    const int wn1  = wn & 1;
    const int quad = lane >> 4, l15 = lane & 15;

    const int m0 = blockIdx.y * 256;
    const int n0 = blockIdx.x * 256;

    const int scol = ((lane & 7) * 8) ^ ((lane & 32) ? 16 : 0);

    const int rA0 = RA00 + wm * 16384;
    const int rA1 = RA10 + wm * 16384;
    const int rB0 = RB00 + (wn >> 1) * 16384;
    const int rB1 = RB10 + (wn >> 1) * 16384;

    const bf16* Ab = A + (size_t)m0 * ND;
    const bf16* Bb = Wt + (size_t)n0 * ND;

    f32x4 acc[8][4] = {};
    bf16x8 af[8], bfr[8];

    GEMM256_KLOOP(Ab, Bb)

    #pragma unroll
    for (int ni = 0; ni < 4; ++ni) {
        int colg = n0 + wn * 64 + ni * 16 + l15;
        float bn = bias[colg];
        #pragma unroll
        for (int mi = 0; mi < 8; ++mi)
            #pragma unroll
            for (int r = 0; r < 4; ++r) {
                int mg = m0 + wm * 128 + mi * 16 + quad * 4 + r;
                Out[(size_t)mg * ND + colg] = acc[mi][ni][r] + bn;
            }
    }
}

// ---------------------------------------------------------------------------
extern "C" void kernel_launch(void* const* d_in, const int* in_sizes, int n_in,
                              void* d_out, int out_size, void* d_ws, size_t ws_size,
                              hipStream_t stream)
{
    const float* q  = (const float*)d_in[0];
    const float* k  = (const float*)d_in[1];
    const float* v  = (const float*)d_in[2];
    const float* Wq = (const float*)d_in[3];
    const float* bq = (const float*)d_in[4];
    const float* Wk = (const float*)d_in[5];
    const float* bk = (const float*)d_in[6];
    const float* Wv = (const float*)d_in[7];
    const float* bv = (const float*)d_in[8];
    const float* Wo = (const float*)d_in[9];
    const float* bo = (const float*)d_in[10];
    const float* qw = (const float*)d_in[11];
    const float* kw = (const float*)d_in[12];
    float* out = (float*)d_out;

    const size_t nX = (size_t)NB * NS * ND;   // 16,777,216
    const size_t nW = (size_t)ND * ND;        //  4,194,304

    // ws layout (bf16): Xb[3*nX] | Wb[4*nW] | Qn[nX] | Kn[nX] | Vtp[nX]
    // Ob aliases Xb (Xb dead after qkv_gemm; Ob written by flash_attn).
    bf16* Xb  = (bf16*)d_ws;
    bf16* Wb  = Xb + 3 * nX;
    bf16* Qn  = Wb + 4 * nW;
    bf16* Kn  = Qn + nX;
    bf16* Vtp = Kn + nX;
    bf16* Ob  = Xb;

    cvt_bf16<<<8192, 256, 0, stream>>>(q,  Xb);
    cvt_bf16<<<8192, 256, 0, stream>>>(k,  Xb + nX);
    cvt_bf16<<<8192, 256, 0, stream>>>(v,  Xb + 2 * nX);
    cvt_bf16<<<2048, 256, 0, stream>>>(Wq, Wb);
    cvt_bf16<<<2048, 256, 0, stream>>>(Wk, Wb + nW);
    cvt_bf16<<<2048, 256, 0, stream>>>(Wv, Wb + 2 * nW);
    cvt_bf16<<<2048, 256, 0, stream>>>(Wo, Wb + 3 * nW);

    qkv_gemm<<<dim3(8, 32, 3), dim3(512), 0, stream>>>(
        Xb, Wb, bq, bk, bv, qw, kw, Qn, Kn, Vtp);
    flash_attn<<<dim3(32, 16, 4), dim3(256), 0, stream>>>(Qn, Kn, Vtp, Ob);
    oproj_gemm<<<dim3(8, 32), dim3(512), 0, stream>>>(Ob, Wb + 3 * nW, bo, out);
}

// Round 3
// 739.198 us; speedup vs baseline: 1.3943x; 1.0491x over previous
//
#include <hip/hip_runtime.h>

#define NB 4
#define NS 2048
#define ND 2048
#define NH 16
#define NHD 128

typedef __bf16 bf16;
typedef __attribute__((ext_vector_type(8))) __bf16 bf16x8;
typedef __attribute__((ext_vector_type(4))) __bf16 bf16x4;
typedef __attribute__((ext_vector_type(4))) float f32x4;
typedef __attribute__((ext_vector_type(16))) float f32x16;

#define MFMA(a, b, c) __builtin_amdgcn_mfma_f32_16x16x32_bf16(a, b, c, 0, 0, 0)
#define MFMA32(a, b, c) __builtin_amdgcn_mfma_f32_32x32x16_bf16(a, b, c, 0, 0, 0)

// async global->LDS, 16 B per lane. LDS dest = wave-uniform base + lane*16.
__device__ __forceinline__ void gload16(const bf16* g, bf16* l) {
    __builtin_amdgcn_global_load_lds(
        (const __attribute__((address_space(1))) void*)g,
        (__attribute__((address_space(3))) void*)l, 16, 0, 0);
}

#define BAR() do { asm volatile("" ::: "memory"); __builtin_amdgcn_s_barrier(); \
                   asm volatile("" ::: "memory"); } while (0)
#define VMCNT4() asm volatile("s_waitcnt vmcnt(4)" ::: "memory")
#define VMCNT0() asm volatile("s_waitcnt vmcnt(0)" ::: "memory")

// ---------------------------------------------------------------------------
// 256x256x64 8-phase GEMM machinery (plain-HIP port of the HK cdna4 schedule)
// ---------------------------------------------------------------------------
enum { RA00 = 0, RA01 = 16384, RA10 = 32768, RA11 = 49152,
       RB00 = 65536, RB01 = 81920, RB10 = 98304, RB11 = 114688 };

__device__ __forceinline__ void stage_half(const bf16* gcorner, char* lds_region,
                                           int w, int lane, int scol) {
    const bf16* g = gcorner + (size_t)(w * 16 + (lane >> 3)) * ND + scol;
    gload16(g, (bf16*)(lds_region + w * 2048));
    gload16(g + (size_t)8 * ND, (bf16*)(lds_region + w * 2048 + 1024));
}

__device__ __forceinline__ void lds_loadA(const char* pool, int region, int mi0,
                                          int l15, int quad, bf16x8 (&af)[8]) {
    const int flip = (l15 & 4) << 3;
    #pragma unroll
    for (int mi = 0; mi < 4; ++mi) {
        const int rb = region + ((mi0 + mi) * 16 + l15) * 128;
        #pragma unroll
        for (int kk = 0; kk < 2; ++kk)
            af[mi * 2 + kk] = *reinterpret_cast<const bf16x8*>(
                pool + rb + ((kk * 64 + quad * 16) ^ flip));
    }
}

template <int NI0>
__device__ __forceinline__ void lds_loadB(const char* pool, int region, int wn1,
                                          int l15, int quad, bf16x8 (&bfr)[8]) {
    const int flip = (l15 & 4) << 3;
    #pragma unroll
    for (int ni = 0; ni < 2; ++ni) {
        const int rb = region + (wn1 * 64 + (NI0 + ni) * 16 + l15) * 128;
        #pragma unroll
        for (int kk = 0; kk < 2; ++kk)
            bfr[(NI0 + ni) * 2 + kk] = *reinterpret_cast<const bf16x8*>(
                pool + rb + ((kk * 64 + quad * 16) ^ flip));
    }
}

template <int MI0, int NI0>
__device__ __forceinline__ void mfma_quad(f32x4 (&acc)[8][4], const bf16x8 (&af)[8],
                                          const bf16x8 (&bfr)[8]) {
    __builtin_amdgcn_s_setprio(1);
    #pragma unroll
    for (int mi = 0; mi < 4; ++mi)
        #pragma unroll
        for (int ni = 0; ni < 2; ++ni)
            #pragma unroll
            for (int kk = 0; kk < 2; ++kk)
                acc[MI0 + mi][NI0 + ni] =
                    MFMA(af[mi * 2 + kk], bfr[(NI0 + ni) * 2 + kk], acc[MI0 + mi][NI0 + ni]);
    __builtin_amdgcn_s_setprio(0);
}

#define GEMM256_KLOOP(Ab, Bb)                                                        \
    stage_half(Ab, pool + RA00, w, lane, scol);                                      \
    stage_half(Ab + (size_t)128 * ND, pool + RA01, w, lane, scol);                   \
    stage_half(Bb, pool + RB00, w, lane, scol);                                      \
    stage_half(Bb + (size_t)128 * ND, pool + RB01, w, lane, scol);                   \
    stage_half(Bb + 64, pool + RB10, w, lane, scol);                                 \
    stage_half(Bb + (size_t)128 * ND + 64, pool + RB11, w, lane, scol);              \
    VMCNT4();                                                                        \
    BAR();                                                                           \
    for (int i = 0; i < 16; ++i) {                                                   \
        const int kA = (2 * i + 1) * 64;                                             \
        const int kN = (2 * i + 2) * 64;                                             \
        const int kN3 = (2 * i + 3) * 64;                                            \
        /* P1 */                                                                     \
        lds_loadA(pool, rA0, 0, l15, quad, af);                                      \
        lds_loadB<0>(pool, rB0, wn1, l15, quad, bfr);                                \
        stage_half(Ab + kA, pool + RA10, w, lane, scol);                             \
        BAR(); mfma_quad<0, 0>(acc, af, bfr); BAR();                                 \
        /* P2 */                                                                     \
        lds_loadB<2>(pool, rB0, wn1, l15, quad, bfr);                                \
        stage_half(Ab + (size_t)128 * ND + kA, pool + RA11, w, lane, scol);          \
        BAR(); mfma_quad<0, 2>(acc, af, bfr); BAR();                                 \
        /* P3 */                                                                     \
        lds_loadA(pool, rA0, 4, l15, quad, af);                                      \
        stage_half(Bb + kN, pool + RB00, w, lane, scol);                             \
        BAR(); mfma_quad<4, 0>(acc, af, bfr); BAR();                                 \
        /* P4 */                                                                     \
        stage_half(Bb + (size_t)128 * ND + kN, pool + RB01, w, lane, scol);          \
        VMCNT4();                                                                    \
        BAR(); mfma_quad<4, 2>(acc, af, bfr); BAR();                                 \
        /* P5 */                                                                     \
        lds_loadA(pool, rA1, 0, l15, quad, af);                                      \
        lds_loadB<0>(pool, rB1, wn1, l15, quad, bfr);                                \
        stage_half(Ab + kN, pool + RA00, w, lane, scol);                             \
        BAR(); mfma_quad<0, 0>(acc, af, bfr); BAR();                                 \
        /* P6 */                                                                     \
        lds_loadB<2>(pool, rB1, wn1, l15, quad, bfr);                                \
        stage_half(Ab + (size_t)128 * ND + kN, pool + RA01, w, lane, scol);          \
        BAR(); mfma_quad<0, 2>(acc, af, bfr); BAR();                                 \
        /* P7 */                                                                     \
        lds_loadA(pool, rA1, 4, l15, quad, af);                                      \
        stage_half(Bb + kN3, pool + RB10, w, lane, scol);                            \
        BAR(); mfma_quad<4, 0>(acc, af, bfr); BAR();                                 \
        /* P8 */                                                                     \
        stage_half(Bb + (size_t)128 * ND + kN3, pool + RB11, w, lane, scol);         \
        VMCNT4();                                                                    \
        BAR(); mfma_quad<4, 2>(acc, af, bfr); BAR();                                 \
    }

// ---------------------------------------------------------------------------
// Kernel 0: fp32 -> bf16 convert
// ---------------------------------------------------------------------------
__global__ __launch_bounds__(256) void cvt_bf16(const float* __restrict__ src,
                                                bf16* __restrict__ dst)
{
    size_t i = ((size_t)blockIdx.x * 256 + threadIdx.x) * 8;
    float4 a = *reinterpret_cast<const float4*>(src + i);
    float4 b = *reinterpret_cast<const float4*>(src + i + 4);
    bf16x8 o;
    o[0] = (bf16)a.x; o[1] = (bf16)a.y; o[2] = (bf16)a.z; o[3] = (bf16)a.w;
    o[4] = (bf16)b.x; o[5] = (bf16)b.y; o[6] = (bf16)b.z; o[7] = (bf16)b.w;
    *reinterpret_cast<bf16x8*>(dst + i) = o;
}

// ---------------------------------------------------------------------------
// Kernel 1: fused QKV projection + bias + per-head RMSNorm (Q,K), V transposed.
// 256x256 8-phase (unchanged from previous round).
// ---------------------------------------------------------------------------
__global__ __launch_bounds__(512, 2) void qkv_gemm(
    const bf16* __restrict__ Xb, const bf16* __restrict__ Wb,
    const float* __restrict__ bq, const float* __restrict__ bk, const float* __restrict__ bv,
    const float* __restrict__ qw, const float* __restrict__ kw,
    bf16* __restrict__ Oq, bf16* __restrict__ Ok, bf16* __restrict__ Ov)
{
    const int mat = blockIdx.z;
    const bf16* X     = Xb + (size_t)mat * (size_t)NB * NS * ND;
    const bf16* W     = Wb + (size_t)mat * ND * ND;
    const float* bias = (mat == 0) ? bq : (mat == 1) ? bk : bv;
    const float* nw   = (mat == 0) ? qw : kw;
    bf16* Out         = (mat == 0) ? Oq : (mat == 1) ? Ok : Ov;

    __shared__ alignas(1024) char pool[131072];
    __shared__ float red[256][4];
    __shared__ float scl[256][2];

    const int tid  = threadIdx.x;
    const int lane = tid & 63;
    const int w    = tid >> 6;
    const int wm   = w >> 2;
    const int wn   = w & 3;
    const int wn1  = wn & 1;
    const int quad = lane >> 4, l15 = lane & 15;

    const int m0 = blockIdx.y * 256;
    const int n0 = blockIdx.x * 256;

    const int scol = ((lane & 7) * 8) ^ ((lane & 32) ? 16 : 0);

    const int rA0 = RA00 + wm * 16384;
    const int rA1 = RA10 + wm * 16384;
    const int rB0 = RB00 + (wn >> 1) * 16384;
    const int rB1 = RB10 + (wn >> 1) * 16384;

    const bf16* Ab = X + (size_t)m0 * ND;
    const bf16* Bb = W + (size_t)n0 * ND;

    f32x4 acc[8][4] = {};
    bf16x8 af[8], bfr[8];

    GEMM256_KLOOP(Ab, Bb)

    #pragma unroll
    for (int ni = 0; ni < 4; ++ni) {
        float bn = bias[n0 + wn * 64 + ni * 16 + l15];
        #pragma unroll
        for (int mi = 0; mi < 8; ++mi)
            #pragma unroll
            for (int r = 0; r < 4; ++r)
                acc[mi][ni][r] += bn;
    }

    if (mat == 2) {
        bf16 (*Ts)[264] = (bf16(*)[264])pool;
        const int bb = m0 >> 11;
        const int s0 = m0 & (NS - 1);
        #pragma unroll
        for (int h2 = 0; h2 < 2; ++h2) {
            __syncthreads();
            if ((wn >> 1) == h2) {
                #pragma unroll
                for (int mi = 0; mi < 8; ++mi)
                    #pragma unroll
                    for (int ni = 0; ni < 4; ++ni) {
                        bf16x4 t;
                        #pragma unroll
                        for (int r = 0; r < 4; ++r) t[r] = (bf16)acc[mi][ni][r];
                        *reinterpret_cast<bf16x4*>(
                            &Ts[wn1 * 64 + ni * 16 + l15][wm * 128 + mi * 16 + quad * 4]) = t;
                    }
            }
            __syncthreads();
            const size_t obase = ((size_t)bb * NH + (n0 >> 7) + h2) * (size_t)NHD * NS;
            #pragma unroll
            for (int it = 0; it < 8; ++it) {
                int d = it * 16 + (tid >> 5);
                int c = (tid & 31) * 8;
                *reinterpret_cast<bf16x8*>(Out + obase + (size_t)d * NS + s0 + c) =
                    *reinterpret_cast<const bf16x8*>(&Ts[d][c]);
            }
        }
        return;
    }

    #pragma unroll
    for (int mi = 0; mi < 8; ++mi) {
        float ss[4];
        #pragma unroll
        for (int r = 0; r < 4; ++r) {
            float s = 0.f;
            #pragma unroll
            for (int ni = 0; ni < 4; ++ni) { float v = acc[mi][ni][r]; s += v * v; }
            ss[r] = s;
        }
        #pragma unroll
        for (int off = 1; off < 16; off <<= 1)
            #pragma unroll
            for (int r = 0; r < 4; ++r)
                ss[r] += __shfl_xor(ss[r], off);
        if (l15 == 0) {
            #pragma unroll
            for (int r = 0; r < 4; ++r)
                red[wm * 128 + mi * 16 + quad * 4 + r][wn] = ss[r];
        }
    }
    __syncthreads();
    {
        int row = tid >> 1, h2 = tid & 1;
        scl[row][h2] = rsqrtf((red[row][2 * h2] + red[row][2 * h2 + 1]) * (1.0f / 128.0f) + 1e-6f);
    }
    __syncthreads();

    const int hh = (n0 >> 7) + (wn >> 1);
    #pragma unroll
    for (int mi = 0; mi < 8; ++mi) {
        #pragma unroll
        for (int r = 0; r < 4; ++r) {
            int row = wm * 128 + mi * 16 + quad * 4 + r;
            int mg  = m0 + row;
            int bb  = mg >> 11;
            int ssi = mg & (NS - 1);
            size_t base = (((size_t)bb * NH + hh) * NS + ssi) * NHD;
            float sc_r = scl[row][wn >> 1];
            #pragma unroll
            for (int ni = 0; ni < 4; ++ni) {
                int col = (wn * 64 + ni * 16 + l15) & 127;
                Out[base + col] = (bf16)(acc[mi][ni][r] * sc_r * nw[col]);
            }
        }
    }
}

// ---------------------------------------------------------------------------
// Kernel 2: flash attention, m214-style 8-wave / 32x32-MFMA structure.
// One block per (b, h, 256-row q tile); each wave owns 32 q rows. KVBLK=64.
// K/V double-buffered in LDS via global_load_lds with XOR-swizzle (linear
// dest + inverse-swizzled global source + swizzled reads, rule #21).
// Counted vmcnt(4), 2 barriers/tile. Swapped QK^T (mfma32(K,Q)): lane holds
// one full q-row (q = lane&31) -> softmax in-register, 1 shfl_xor per reduce.
// P through per-wave swizzled LDS slab. Defer-max (T13), setprio (T5).
// ---------------------------------------------------------------------------
__global__ __launch_bounds__(512, 2) void flash_attn(
    const bf16* __restrict__ Q, const bf16* __restrict__ K, const bf16* __restrict__ Vt,
    bf16* __restrict__ O)
{
    __shared__ alignas(1024) char kpool[32768];   // 2 x [64 keys][256 B] swizzled
    __shared__ alignas(1024) char vpool[32768];   // 2 x [128 d][128 B] swizzled
    __shared__ alignas(1024) char ppool[32768];   // 8 waves x [32 q][128 B] swizzled

    const int tid  = threadIdx.x;
    const int lane = tid & 63;
    const int w    = tid >> 6;          // 0..7
    const int l31  = lane & 31;
    const int hi   = lane >> 5;         // 0/1
    const int b    = blockIdx.z, h = blockIdx.y;
    const int q0   = blockIdx.x * 256;
    const size_t hb = ((size_t)b * NH + h) * (size_t)NS * NHD;
    const bf16* Qh  = Q + hb;
    const bf16* Kh  = K + hb;
    const bf16* Vth = Vt + hb;          // (b,h,d,s)

    // Q fragments (B-operand): col = q = l31, k = hi*8 + j, slice ks: d = ks*16+...
    bf16x8 qf[8];
    {
        const bf16* qrow = Qh + (size_t)(q0 + w * 32 + l31) * NHD + hi * 8;
        #pragma unroll
        for (int ks = 0; ks < 8; ++ks)
            qf[ks] = *reinterpret_cast<const bf16x8*>(qrow + ks * 16);
    }

    char* Psb = ppool + w * 4096;       // this wave's 32x64 P slab
    const int swz = (l31 & 7) << 4;
    const int qrow_b = l31 * 128;

    f32x16 o0 = {}, o1 = {}, o2 = {}, o3 = {};   // o[dt]: D[q'][d = dt*32 + l31]
    float m_r = -1e30f, l_r = 0.f;
    const float C = 0.12751740f;        // (1/sqrt(128)) * log2(e)

    // staging: 4 gload_lds per wave per tile (K: 2 x 1KB chunks, V: 2 x 1KB)
    auto stage_tile = [&](int t, int bufsel) {
        const bf16* Kt  = Kh  + (size_t)(t & 31) * 64 * NHD;
        const bf16* Vtt = Vth + (size_t)(t & 31) * 64;
        char* Kb = kpool + bufsel * 16384;
        char* Vb = vpool + bufsel * 16384;
        #pragma unroll
        for (int j = 0; j < 2; ++j) {
            int c = w * 2 + j;                      // chunk 0..15
            int krow  = 4 * c + (lane >> 4);
            int kslot = (lane & 15) ^ (4 * (c & 1) + (lane >> 4));
            gload16(Kt + (size_t)krow * NHD + kslot * 8, (bf16*)(Kb + c * 1024));
            int vrow  = 8 * c + (lane >> 3);
            int vslot = (lane & 7) ^ (lane >> 3);
            gload16(Vtt + (size_t)vrow * NS + vslot * 8, (bf16*)(Vb + c * 1024));
        }
    };

    stage_tile(0, 0);

    const int NT = NS / 64;
    for (int kt = 0; kt < NT; ++kt) {
        const int cur = kt & 1;
        if (kt + 1 < NT) {
            stage_tile(kt + 1, cur ^ 1);
            VMCNT4();
        } else {
            VMCNT0();
        }
        BAR();                                     // tile kt fully in LDS

        const char* Kb = kpool + cur * 16384;
        const char* Vb = vpool + cur * 16384;

        // S^T = K Q^T : s0 = keys 0-31, s1 = keys 32-63 (rows); q = col = l31
        f32x16 s0 = {}, s1 = {};
        __builtin_amdgcn_s_setprio(1);
        #pragma unroll
        for (int ks = 0; ks < 8; ++ks) {
            const int co = ks * 32 + hi * 16;
            bf16x8 k0 = *reinterpret_cast<const bf16x8*>(
                Kb + l31 * 256 + (co ^ swz));
            bf16x8 k1 = *reinterpret_cast<const bf16x8*>(
                Kb + (32 + l31) * 256 + (co ^ swz));
            s0 = MFMA32(k0, qf[ks], s0);
            s1 = MFMA32(k1, qf[ks], s1);
        }
        __builtin_amdgcn_s_setprio(0);

        // ---- in-register online softmax (one q-row per lane) ----
        float mt = s0[0];
        #pragma unroll
        for (int r = 1; r < 16; ++r) mt = fmaxf(mt, s0[r]);
        #pragma unroll
        for (int r = 0; r < 16; ++r) mt = fmaxf(mt, s1[r]);
        mt = fmaxf(mt, __shfl_xor(mt, 32));

        const bool grow = !__all(mt - m_r <= 64.0f);
        float alpha = 1.f;
        if (grow) {
            float mn = fmaxf(m_r, mt);
            alpha = __builtin_amdgcn_exp2f((m_r - mn) * C);
            m_r = mn;
        }
        const float mC = m_r * C;
        float rs = 0.f;
        #pragma unroll
        for (int r = 0; r < 16; ++r) { s0[r] = __builtin_amdgcn_exp2f(s0[r] * C - mC); rs += s0[r]; }
        #pragma unroll
        for (int r = 0; r < 16; ++r) { s1[r] = __builtin_amdgcn_exp2f(s1[r] * C - mC); rs += s1[r]; }
        rs += __shfl_xor(rs, 32);
        l_r = l_r * alpha + rs;

        // P -> per-wave LDS slab (key(r) = (r&3) + 8*(r>>2) + 4*hi [+32 for s1])
        #pragma unroll
        for (int g = 0; g < 4; ++g) {
            bf16x4 t0, t1;
            #pragma unroll
            for (int j = 0; j < 4; ++j) {
                t0[j] = (bf16)s0[g * 4 + j];
                t1[j] = (bf16)s1[g * 4 + j];
            }
            *reinterpret_cast<bf16x4*>(Psb + qrow_b + ((g * 16 + hi * 8) ^ swz)) = t0;
            *reinterpret_cast<bf16x4*>(Psb + qrow_b + ((64 + g * 16 + hi * 8) ^ swz)) = t1;
        }

        if (grow) {     // wave-uniform; rare under defer-max
            #pragma unroll
            for (int r = 0; r < 16; ++r) {
                float av = __shfl(alpha, (r & 3) + 8 * (r >> 2) + 4 * hi);
                o0[r] *= av; o1[r] *= av; o2[r] *= av; o3[r] *= av;
            }
        }

        // O += P @ V : A = P[q][k] (row = q = l31), B = V[k][d] (col = d = l31)
        __builtin_amdgcn_s_setprio(1);
        #pragma unroll
        for (int ks = 0; ks < 4; ++ks) {
            const int co = ks * 32 + hi * 16;
            bf16x8 pa = *reinterpret_cast<const bf16x8*>(Psb + qrow_b + (co ^ swz));
            bf16x8 v0 = *reinterpret_cast<const bf16x8*>(Vb + l31 * 128 + (co ^ swz));
            bf16x8 v1 = *reinterpret_cast<const bf16x8*>(Vb + (32 + l31) * 128 + (co ^ swz));
            bf16x8 v2 = *reinterpret_cast<const bf16x8*>(Vb + (64 + l31) * 128 + (co ^ swz));
            bf16x8 v3 = *reinterpret_cast<const bf16x8*>(Vb + (96 + l31) * 128 + (co ^ swz));
            o0 = MFMA32(pa, v0, o0);
            o1 = MFMA32(pa, v1, o1);
            o2 = MFMA32(pa, v2, o2);
            o3 = MFMA32(pa, v3, o3);
        }
        __builtin_amdgcn_s_setprio(0);

        BAR();                                     // all reads of buf cur done
    }

    // epilogue: O /= l, write (B,S,D) bf16. Row q' = (r&3)+8*(r>>2)+4*hi.
    #pragma unroll
    for (int r = 0; r < 16; ++r) {
        int qp = (r & 3) + 8 * (r >> 2) + 4 * hi;
        float inv = 1.0f / __shfl(l_r, qp);
        int sg = q0 + w * 32 + qp;
        size_t base = ((size_t)b * NS + sg) * ND + (size_t)h * NHD + l31;
        O[base]      = (bf16)(o0[r] * inv);
        O[base + 32] = (bf16)(o1[r] * inv);
        O[base + 64] = (bf16)(o2[r] * inv);
        O[base + 96] = (bf16)(o3[r] * inv);
    }
}

// ---------------------------------------------------------------------------
// Kernel 3: output projection, 256x256 8-phase (unchanged).
// ---------------------------------------------------------------------------
__global__ __launch_bounds__(512, 2) void oproj_gemm(
    const bf16* __restrict__ A, const bf16* __restrict__ Wt,
    const float* __restrict__ bias, float* __restrict__ Out)
{
    __shared__ alignas(1024) char pool[131072];

    const int tid  = threadIdx.x;
    const int lane = tid & 63;
    const int w    = tid >> 6;
    const int wm   = w >> 2;
    const int wn   = w & 3;
    const int wn1  = wn & 1;
    const int quad = lane >> 4, l15 = lane & 15;

    const int m0 = blockIdx.y * 256;
    const int n0 = blockIdx.x * 256;

    const int scol = ((lane & 7) * 8) ^ ((lane & 32) ? 16 : 0);

    const int rA0 = RA00 + wm * 16384;
    const int rA1 = RA10 + wm * 16384;
    const int rB0 = RB00 + (wn >> 1) * 16384;
    const int rB1 = RB10 + (wn >> 1) * 16384;

    const bf16* Ab = A + (size_t)m0 * ND;
    const bf16* Bb = Wt + (size_t)n0 * ND;

    f32x4 acc[8][4] = {};
    bf16x8 af[8], bfr[8];

    GEMM256_KLOOP(Ab, Bb)

    #pragma unroll
    for (int ni = 0; ni < 4; ++ni) {
        int colg = n0 + wn * 64 + ni * 16 + l15;
        float bn = bias[colg];
        #pragma unroll
        for (int mi = 0; mi < 8; ++mi)
            #pragma unroll
            for (int r = 0; r < 4; ++r) {
                int mg = m0 + wm * 128 + mi * 16 + quad * 4 + r;
                Out[(size_t)mg * ND + colg] = acc[mi][ni][r] + bn;
            }
    }
}

// ---------------------------------------------------------------------------
extern "C" void kernel_launch(void* const* d_in, const int* in_sizes, int n_in,
                              void* d_out, int out_size, void* d_ws, size_t ws_size,
                              hipStream_t stream)
{
    const float* q  = (const float*)d_in[0];
    const float* k  = (const float*)d_in[1];
    const float* v  = (const float*)d_in[2];
    const float* Wq = (const float*)d_in[3];
    const float* bq = (const float*)d_in[4];
    const float* Wk = (const float*)d_in[5];
    const float* bk = (const float*)d_in[6];
    const float* Wv = (const float*)d_in[7];
    const float* bv = (const float*)d_in[8];
    const float* Wo = (const float*)d_in[9];
    const float* bo = (const float*)d_in[10];
    const float* qw = (const float*)d_in[11];
    const float* kw = (const float*)d_in[12];
    float* out = (float*)d_out;

    const size_t nX = (size_t)NB * NS * ND;   // 16,777,216
    const size_t nW = (size_t)ND * ND;        //  4,194,304

    bf16* Xb  = (bf16*)d_ws;
    bf16* Wb  = Xb + 3 * nX;
    bf16* Qn  = Wb + 4 * nW;
    bf16* Kn  = Qn + nX;
    bf16* Vtp = Kn + nX;
    bf16* Ob  = Xb;

    cvt_bf16<<<8192, 256, 0, stream>>>(q,  Xb);
    cvt_bf16<<<8192, 256, 0, stream>>>(k,  Xb + nX);
    cvt_bf16<<<8192, 256, 0, stream>>>(v,  Xb + 2 * nX);
    cvt_bf16<<<2048, 256, 0, stream>>>(Wq, Wb);
    cvt_bf16<<<2048, 256, 0, stream>>>(Wk, Wb + nW);
    cvt_bf16<<<2048, 256, 0, stream>>>(Wv, Wb + 2 * nW);
    cvt_bf16<<<2048, 256, 0, stream>>>(Wo, Wb + 3 * nW);

    qkv_gemm<<<dim3(8, 32, 3), dim3(512), 0, stream>>>(
        Xb, Wb, bq, bk, bv, qw, kw, Qn, Kn, Vtp);
    flash_attn<<<dim3(8, 16, 4), dim3(512), 0, stream>>>(Qn, Kn, Vtp, Ob);
    oproj_gemm<<<dim3(8, 32), dim3(512), 0, stream>>>(Ob, Wb + 3 * nW, bo, out);
}

// Round 4
// 714.920 us; speedup vs baseline: 1.4417x; 1.0340x over previous
//
#include <hip/hip_runtime.h>

#define NB 4
#define NS 2048
#define ND 2048
#define NH 16
#define NHD 128

typedef __bf16 bf16;
typedef __attribute__((ext_vector_type(8))) __bf16 bf16x8;
typedef __attribute__((ext_vector_type(4))) __bf16 bf16x4;
typedef __attribute__((ext_vector_type(4))) float f32x4;
typedef __attribute__((ext_vector_type(16))) float f32x16;

#define MFMA(a, b, c) __builtin_amdgcn_mfma_f32_16x16x32_bf16(a, b, c, 0, 0, 0)
#define MFMA32(a, b, c) __builtin_amdgcn_mfma_f32_32x32x16_bf16(a, b, c, 0, 0, 0)

// async global->LDS, 16 B per lane. LDS dest = wave-uniform base + lane*16.
__device__ __forceinline__ void gload16(const bf16* g, bf16* l) {
    __builtin_amdgcn_global_load_lds(
        (const __attribute__((address_space(1))) void*)g,
        (__attribute__((address_space(3))) void*)l, 16, 0, 0);
}

#define BAR() do { asm volatile("" ::: "memory"); __builtin_amdgcn_s_barrier(); \
                   asm volatile("" ::: "memory"); } while (0)
#define VMCNT4() asm volatile("s_waitcnt vmcnt(4)" ::: "memory")
#define VMCNT0() asm volatile("s_waitcnt vmcnt(0)" ::: "memory")

// ---------------------------------------------------------------------------
// 256x256x64 8-phase GEMM machinery (plain-HIP port of the HK cdna4 schedule)
// ---------------------------------------------------------------------------
enum { RA00 = 0, RA01 = 16384, RA10 = 32768, RA11 = 49152,
       RB00 = 65536, RB01 = 81920, RB10 = 98304, RB11 = 114688 };

__device__ __forceinline__ void stage_half(const bf16* gcorner, char* lds_region,
                                           int w, int lane, int scol) {
    const bf16* g = gcorner + (size_t)(w * 16 + (lane >> 3)) * ND + scol;
    gload16(g, (bf16*)(lds_region + w * 2048));
    gload16(g + (size_t)8 * ND, (bf16*)(lds_region + w * 2048 + 1024));
}

__device__ __forceinline__ void lds_loadA(const char* pool, int region, int mi0,
                                          int l15, int quad, bf16x8 (&af)[8]) {
    const int flip = (l15 & 4) << 3;
    #pragma unroll
    for (int mi = 0; mi < 4; ++mi) {
        const int rb = region + ((mi0 + mi) * 16 + l15) * 128;
        #pragma unroll
        for (int kk = 0; kk < 2; ++kk)
            af[mi * 2 + kk] = *reinterpret_cast<const bf16x8*>(
                pool + rb + ((kk * 64 + quad * 16) ^ flip));
    }
}

template <int NI0>
__device__ __forceinline__ void lds_loadB(const char* pool, int region, int wn1,
                                          int l15, int quad, bf16x8 (&bfr)[8]) {
    const int flip = (l15 & 4) << 3;
    #pragma unroll
    for (int ni = 0; ni < 2; ++ni) {
        const int rb = region + (wn1 * 64 + (NI0 + ni) * 16 + l15) * 128;
        #pragma unroll
        for (int kk = 0; kk < 2; ++kk)
            bfr[(NI0 + ni) * 2 + kk] = *reinterpret_cast<const bf16x8*>(
                pool + rb + ((kk * 64 + quad * 16) ^ flip));
    }
}

template <int MI0, int NI0>
__device__ __forceinline__ void mfma_quad(f32x4 (&acc)[8][4], const bf16x8 (&af)[8],
                                          const bf16x8 (&bfr)[8]) {
    __builtin_amdgcn_s_setprio(1);
    #pragma unroll
    for (int mi = 0; mi < 4; ++mi)
        #pragma unroll
        for (int ni = 0; ni < 2; ++ni)
            #pragma unroll
            for (int kk = 0; kk < 2; ++kk)
                acc[MI0 + mi][NI0 + ni] =
                    MFMA(af[mi * 2 + kk], bfr[(NI0 + ni) * 2 + kk], acc[MI0 + mi][NI0 + ni]);
    __builtin_amdgcn_s_setprio(0);
}

#define GEMM256_KLOOP(Ab, Bb)                                                        \
    stage_half(Ab, pool + RA00, w, lane, scol);                                      \
    stage_half(Ab + (size_t)128 * ND, pool + RA01, w, lane, scol);                   \
    stage_half(Bb, pool + RB00, w, lane, scol);                                      \
    stage_half(Bb + (size_t)128 * ND, pool + RB01, w, lane, scol);                   \
    stage_half(Bb + 64, pool + RB10, w, lane, scol);                                 \
    stage_half(Bb + (size_t)128 * ND + 64, pool + RB11, w, lane, scol);              \
    VMCNT4();                                                                        \
    BAR();                                                                           \
    for (int i = 0; i < 16; ++i) {                                                   \
        const int kA = (2 * i + 1) * 64;                                             \
        const int kN = (2 * i + 2) * 64;                                             \
        const int kN3 = (2 * i + 3) * 64;                                            \
        /* P1 */                                                                     \
        lds_loadA(pool, rA0, 0, l15, quad, af);                                      \
        lds_loadB<0>(pool, rB0, wn1, l15, quad, bfr);                                \
        stage_half(Ab + kA, pool + RA10, w, lane, scol);                             \
        BAR(); mfma_quad<0, 0>(acc, af, bfr); BAR();                                 \
        /* P2 */                                                                     \
        lds_loadB<2>(pool, rB0, wn1, l15, quad, bfr);                                \
        stage_half(Ab + (size_t)128 * ND + kA, pool + RA11, w, lane, scol);          \
        BAR(); mfma_quad<0, 2>(acc, af, bfr); BAR();                                 \
        /* P3 */                                                                     \
        lds_loadA(pool, rA0, 4, l15, quad, af);                                      \
        stage_half(Bb + kN, pool + RB00, w, lane, scol);                             \
        BAR(); mfma_quad<4, 0>(acc, af, bfr); BAR();                                 \
        /* P4 */                                                                     \
        stage_half(Bb + (size_t)128 * ND + kN, pool + RB01, w, lane, scol);          \
        VMCNT4();                                                                    \
        BAR(); mfma_quad<4, 2>(acc, af, bfr); BAR();                                 \
        /* P5 */                                                                     \
        lds_loadA(pool, rA1, 0, l15, quad, af);                                      \
        lds_loadB<0>(pool, rB1, wn1, l15, quad, bfr);                                \
        stage_half(Ab + kN, pool + RA00, w, lane, scol);                             \
        BAR(); mfma_quad<0, 0>(acc, af, bfr); BAR();                                 \
        /* P6 */                                                                     \
        lds_loadB<2>(pool, rB1, wn1, l15, quad, bfr);                                \
        stage_half(Ab + (size_t)128 * ND + kN, pool + RA01, w, lane, scol);          \
        BAR(); mfma_quad<0, 2>(acc, af, bfr); BAR();                                 \
        /* P7 */                                                                     \
        lds_loadA(pool, rA1, 4, l15, quad, af);                                      \
        stage_half(Bb + kN3, pool + RB10, w, lane, scol);                            \
        BAR(); mfma_quad<4, 0>(acc, af, bfr); BAR();                                 \
        /* P8 */                                                                     \
        stage_half(Bb + (size_t)128 * ND + kN3, pool + RB11, w, lane, scol);         \
        VMCNT4();                                                                    \
        BAR(); mfma_quad<4, 2>(acc, af, bfr); BAR();                                 \
    }

// ---------------------------------------------------------------------------
// Kernel 0: fused fp32 -> bf16 convert for all 7 tensors (one launch).
// Block ranges: [0,8192)q [8192,16384)k [16384,24576)v then 4x2048 for W's.
// ---------------------------------------------------------------------------
__global__ __launch_bounds__(256) void cvt_all(
    const float* __restrict__ q, const float* __restrict__ k, const float* __restrict__ v,
    const float* __restrict__ Wq, const float* __restrict__ Wk,
    const float* __restrict__ Wv, const float* __restrict__ Wo,
    bf16* __restrict__ Xb, bf16* __restrict__ Wb)
{
    const size_t nX = (size_t)NB * NS * ND;
    const size_t nW = (size_t)ND * ND;
    int bid = blockIdx.x;
    const float* src; bf16* dst;
    if (bid < 24576) {
        int sel = bid >> 13;
        src = (sel == 0) ? q : (sel == 1) ? k : v;
        dst = Xb + (size_t)sel * nX;
        bid &= 8191;
    } else {
        int sel = (bid - 24576) >> 11;
        src = (sel == 0) ? Wq : (sel == 1) ? Wk : (sel == 2) ? Wv : Wo;
        dst = Wb + (size_t)sel * nW;
        bid = (bid - 24576) & 2047;
    }
    size_t i = ((size_t)bid * 256 + threadIdx.x) * 8;
    float4 a = *reinterpret_cast<const float4*>(src + i);
    float4 b = *reinterpret_cast<const float4*>(src + i + 4);
    bf16x8 o;
    o[0] = (bf16)a.x; o[1] = (bf16)a.y; o[2] = (bf16)a.z; o[3] = (bf16)a.w;
    o[4] = (bf16)b.x; o[5] = (bf16)b.y; o[6] = (bf16)b.z; o[7] = (bf16)b.w;
    *reinterpret_cast<bf16x8*>(dst + i) = o;
}

// XCD-chunked remap for the 32m x 8n GEMM grids: hardware flat id f -> tile.
// XCD c (= f%8) owns m in [c*4, c*4+4) x all 8 n; n varies fastest so each
// A-panel (1 MB) is L2-reused 8x and W panels L3-persist. Bijective.
__device__ __forceinline__ void gemm_remap(int flat, int& m0, int& n0) {
    int xcd = flat & 7;
    int idx = flat >> 3;
    m0 = (xcd * 4 + (idx >> 3)) * 256;
    n0 = (idx & 7) * 256;
}

// ---------------------------------------------------------------------------
// Kernel 1: fused QKV projection + bias + per-head RMSNorm (Q,K), V transposed.
// 256x256 8-phase + XCD-chunked block remap.
// ---------------------------------------------------------------------------
__global__ __launch_bounds__(512, 2) void qkv_gemm(
    const bf16* __restrict__ Xb, const bf16* __restrict__ Wb,
    const float* __restrict__ bq, const float* __restrict__ bk, const float* __restrict__ bv,
    const float* __restrict__ qw, const float* __restrict__ kw,
    bf16* __restrict__ Oq, bf16* __restrict__ Ok, bf16* __restrict__ Ov)
{
    const int mat = blockIdx.z;
    const bf16* X     = Xb + (size_t)mat * (size_t)NB * NS * ND;
    const bf16* W     = Wb + (size_t)mat * ND * ND;
    const float* bias = (mat == 0) ? bq : (mat == 1) ? bk : bv;
    const float* nw   = (mat == 0) ? qw : kw;
    bf16* Out         = (mat == 0) ? Oq : (mat == 1) ? Ok : Ov;

    __shared__ alignas(1024) char pool[131072];
    __shared__ float red[256][4];
    __shared__ float scl[256][2];

    const int tid  = threadIdx.x;
    const int lane = tid & 63;
    const int w    = tid >> 6;
    const int wm   = w >> 2;
    const int wn   = w & 3;
    const int wn1  = wn & 1;
    const int quad = lane >> 4, l15 = lane & 15;

    int m0, n0;
    gemm_remap(blockIdx.y * 8 + blockIdx.x, m0, n0);

    const int scol = ((lane & 7) * 8) ^ ((lane & 32) ? 16 : 0);

    const int rA0 = RA00 + wm * 16384;
    const int rA1 = RA10 + wm * 16384;
    const int rB0 = RB00 + (wn >> 1) * 16384;
    const int rB1 = RB10 + (wn >> 1) * 16384;

    const bf16* Ab = X + (size_t)m0 * ND;
    const bf16* Bb = W + (size_t)n0 * ND;

    f32x4 acc[8][4] = {};
    bf16x8 af[8], bfr[8];

    GEMM256_KLOOP(Ab, Bb)

    #pragma unroll
    for (int ni = 0; ni < 4; ++ni) {
        float bn = bias[n0 + wn * 64 + ni * 16 + l15];
        #pragma unroll
        for (int mi = 0; mi < 8; ++mi)
            #pragma unroll
            for (int r = 0; r < 4; ++r)
                acc[mi][ni][r] += bn;
    }

    if (mat == 2) {
        bf16 (*Ts)[264] = (bf16(*)[264])pool;
        const int bb = m0 >> 11;
        const int s0 = m0 & (NS - 1);
        #pragma unroll
        for (int h2 = 0; h2 < 2; ++h2) {
            __syncthreads();
            if ((wn >> 1) == h2) {
                #pragma unroll
                for (int mi = 0; mi < 8; ++mi)
                    #pragma unroll
                    for (int ni = 0; ni < 4; ++ni) {
                        bf16x4 t;
                        #pragma unroll
                        for (int r = 0; r < 4; ++r) t[r] = (bf16)acc[mi][ni][r];
                        *reinterpret_cast<bf16x4*>(
                            &Ts[wn1 * 64 + ni * 16 + l15][wm * 128 + mi * 16 + quad * 4]) = t;
                    }
            }
            __syncthreads();
            const size_t obase = ((size_t)bb * NH + (n0 >> 7) + h2) * (size_t)NHD * NS;
            #pragma unroll
            for (int it = 0; it < 8; ++it) {
                int d = it * 16 + (tid >> 5);
                int c = (tid & 31) * 8;
                *reinterpret_cast<bf16x8*>(Out + obase + (size_t)d * NS + s0 + c) =
                    *reinterpret_cast<const bf16x8*>(&Ts[d][c]);
            }
        }
        return;
    }

    #pragma unroll
    for (int mi = 0; mi < 8; ++mi) {
        float ss[4];
        #pragma unroll
        for (int r = 0; r < 4; ++r) {
            float s = 0.f;
            #pragma unroll
            for (int ni = 0; ni < 4; ++ni) { float v = acc[mi][ni][r]; s += v * v; }
            ss[r] = s;
        }
        #pragma unroll
        for (int off = 1; off < 16; off <<= 1)
            #pragma unroll
            for (int r = 0; r < 4; ++r)
                ss[r] += __shfl_xor(ss[r], off);
        if (l15 == 0) {
            #pragma unroll
            for (int r = 0; r < 4; ++r)
                red[wm * 128 + mi * 16 + quad * 4 + r][wn] = ss[r];
        }
    }
    __syncthreads();
    {
        int row = tid >> 1, h2 = tid & 1;
        scl[row][h2] = rsqrtf((red[row][2 * h2] + red[row][2 * h2 + 1]) * (1.0f / 128.0f) + 1e-6f);
    }
    __syncthreads();

    const int hh = (n0 >> 7) + (wn >> 1);
    #pragma unroll
    for (int mi = 0; mi < 8; ++mi) {
        #pragma unroll
        for (int r = 0; r < 4; ++r) {
            int row = wm * 128 + mi * 16 + quad * 4 + r;
            int mg  = m0 + row;
            int bb  = mg >> 11;
            int ssi = mg & (NS - 1);
            size_t base = (((size_t)bb * NH + hh) * NS + ssi) * NHD;
            float sc_r = scl[row][wn >> 1];
            #pragma unroll
            for (int ni = 0; ni < 4; ++ni) {
                int col = (wn * 64 + ni * 16 + l15) & 127;
                Out[base + col] = (bf16)(acc[mi][ni][r] * sc_r * nw[col]);
            }
        }
    }
}

// ---------------------------------------------------------------------------
// Kernel 2: flash attention, 8-wave / 32x32-MFMA (unchanged schedule) with
// XCD-chunked remap: all 8 q-tiles of one (b,h) share an XCD -> K/V L2-hit.
// ---------------------------------------------------------------------------
__global__ __launch_bounds__(512, 2) void flash_attn(
    const bf16* __restrict__ Q, const bf16* __restrict__ K, const bf16* __restrict__ Vt,
    bf16* __restrict__ O)
{
    __shared__ alignas(1024) char kpool[32768];   // 2 x [64 keys][256 B] swizzled
    __shared__ alignas(1024) char vpool[32768];   // 2 x [128 d][128 B] swizzled
    __shared__ alignas(1024) char ppool[32768];   // 8 waves x [32 q][128 B] swizzled

    const int tid  = threadIdx.x;
    const int lane = tid & 63;
    const int w    = tid >> 6;          // 0..7
    const int l31  = lane & 31;
    const int hi   = lane >> 5;         // 0/1

    // remap: blocks with equal (b,h) share f%8 (== XCD under round-robin)
    const int flat = (blockIdx.z * NH + blockIdx.y) * gridDim.x + blockIdx.x;
    const int qt   = flat >> 6;         // 0..7
    const int bh   = flat & 63;
    const int b    = bh >> 4, h = bh & 15;
    const int q0   = qt * 256;

    const size_t hb = ((size_t)b * NH + h) * (size_t)NS * NHD;
    const bf16* Qh  = Q + hb;
    const bf16* Kh  = K + hb;
    const bf16* Vth = Vt + hb;          // (b,h,d,s)

    bf16x8 qf[8];
    {
        const bf16* qrow = Qh + (size_t)(q0 + w * 32 + l31) * NHD + hi * 8;
        #pragma unroll
        for (int ks = 0; ks < 8; ++ks)
            qf[ks] = *reinterpret_cast<const bf16x8*>(qrow + ks * 16);
    }

    char* Psb = ppool + w * 4096;       // this wave's 32x64 P slab
    const int swz = (l31 & 7) << 4;
    const int qrow_b = l31 * 128;

    f32x16 o0 = {}, o1 = {}, o2 = {}, o3 = {};
    float m_r = -1e30f, l_r = 0.f;
    const float C = 0.12751740f;        // (1/sqrt(128)) * log2(e)

    auto stage_tile = [&](int t, int bufsel) {
        const bf16* Kt  = Kh  + (size_t)(t & 31) * 64 * NHD;
        const bf16* Vtt = Vth + (size_t)(t & 31) * 64;
        char* Kb = kpool + bufsel * 16384;
        char* Vb = vpool + bufsel * 16384;
        #pragma unroll
        for (int j = 0; j < 2; ++j) {
            int c = w * 2 + j;
            int krow  = 4 * c + (lane >> 4);
            int kslot = (lane & 15) ^ (4 * (c & 1) + (lane >> 4));
            gload16(Kt + (size_t)krow * NHD + kslot * 8, (bf16*)(Kb + c * 1024));
            int vrow  = 8 * c + (lane >> 3);
            int vslot = (lane & 7) ^ (lane >> 3);
            gload16(Vtt + (size_t)vrow * NS + vslot * 8, (bf16*)(Vb + c * 1024));
        }
    };

    stage_tile(0, 0);

    const int NT = NS / 64;
    for (int kt = 0; kt < NT; ++kt) {
        const int cur = kt & 1;
        if (kt + 1 < NT) {
            stage_tile(kt + 1, cur ^ 1);
            VMCNT4();
        } else {
            VMCNT0();
        }
        BAR();

        const char* Kb = kpool + cur * 16384;
        const char* Vb = vpool + cur * 16384;

        f32x16 s0 = {}, s1 = {};
        __builtin_amdgcn_s_setprio(1);
        #pragma unroll
        for (int ks = 0; ks < 8; ++ks) {
            const int co = ks * 32 + hi * 16;
            bf16x8 k0 = *reinterpret_cast<const bf16x8*>(
                Kb + l31 * 256 + (co ^ swz));
            bf16x8 k1 = *reinterpret_cast<const bf16x8*>(
                Kb + (32 + l31) * 256 + (co ^ swz));
            s0 = MFMA32(k0, qf[ks], s0);
            s1 = MFMA32(k1, qf[ks], s1);
        }
        __builtin_amdgcn_s_setprio(0);

        float mt = s0[0];
        #pragma unroll
        for (int r = 1; r < 16; ++r) mt = fmaxf(mt, s0[r]);
        #pragma unroll
        for (int r = 0; r < 16; ++r) mt = fmaxf(mt, s1[r]);
        mt = fmaxf(mt, __shfl_xor(mt, 32));

        const bool grow = !__all(mt - m_r <= 64.0f);
        float alpha = 1.f;
        if (grow) {
            float mn = fmaxf(m_r, mt);
            alpha = __builtin_amdgcn_exp2f((m_r - mn) * C);
            m_r = mn;
        }
        const float mC = m_r * C;
        float rs = 0.f;
        #pragma unroll
        for (int r = 0; r < 16; ++r) { s0[r] = __builtin_amdgcn_exp2f(s0[r] * C - mC); rs += s0[r]; }
        #pragma unroll
        for (int r = 0; r < 16; ++r) { s1[r] = __builtin_amdgcn_exp2f(s1[r] * C - mC); rs += s1[r]; }
        rs += __shfl_xor(rs, 32);
        l_r = l_r * alpha + rs;

        #pragma unroll
        for (int g = 0; g < 4; ++g) {
            bf16x4 t0, t1;
            #pragma unroll
            for (int j = 0; j < 4; ++j) {
                t0[j] = (bf16)s0[g * 4 + j];
                t1[j] = (bf16)s1[g * 4 + j];
            }
            *reinterpret_cast<bf16x4*>(Psb + qrow_b + ((g * 16 + hi * 8) ^ swz)) = t0;
            *reinterpret_cast<bf16x4*>(Psb + qrow_b + ((64 + g * 16 + hi * 8) ^ swz)) = t1;
        }

        if (grow) {
            #pragma unroll
            for (int r = 0; r < 16; ++r) {
                float av = __shfl(alpha, (r & 3) + 8 * (r >> 2) + 4 * hi);
                o0[r] *= av; o1[r] *= av; o2[r] *= av; o3[r] *= av;
            }
        }

        __builtin_amdgcn_s_setprio(1);
        #pragma unroll
        for (int ks = 0; ks < 4; ++ks) {
            const int co = ks * 32 + hi * 16;
            bf16x8 pa = *reinterpret_cast<const bf16x8*>(Psb + qrow_b + (co ^ swz));
            bf16x8 v0 = *reinterpret_cast<const bf16x8*>(Vb + l31 * 128 + (co ^ swz));
            bf16x8 v1 = *reinterpret_cast<const bf16x8*>(Vb + (32 + l31) * 128 + (co ^ swz));
            bf16x8 v2 = *reinterpret_cast<const bf16x8*>(Vb + (64 + l31) * 128 + (co ^ swz));
            bf16x8 v3 = *reinterpret_cast<const bf16x8*>(Vb + (96 + l31) * 128 + (co ^ swz));
            o0 = MFMA32(pa, v0, o0);
            o1 = MFMA32(pa, v1, o1);
            o2 = MFMA32(pa, v2, o2);
            o3 = MFMA32(pa, v3, o3);
        }
        __builtin_amdgcn_s_setprio(0);

        BAR();
    }

    #pragma unroll
    for (int r = 0; r < 16; ++r) {
        int qp = (r & 3) + 8 * (r >> 2) + 4 * hi;
        float inv = 1.0f / __shfl(l_r, qp);
        int sg = q0 + w * 32 + qp;
        size_t base = ((size_t)b * NS + sg) * ND + (size_t)h * NHD + l31;
        O[base]      = (bf16)(o0[r] * inv);
        O[base + 32] = (bf16)(o1[r] * inv);
        O[base + 64] = (bf16)(o2[r] * inv);
        O[base + 96] = (bf16)(o3[r] * inv);
    }
}

// ---------------------------------------------------------------------------
// Kernel 3: output projection, 256x256 8-phase + XCD-chunked remap.
// ---------------------------------------------------------------------------
__global__ __launch_bounds__(512, 2) void oproj_gemm(
    const bf16* __restrict__ A, const bf16* __restrict__ Wt,
    const float* __restrict__ bias, float* __restrict__ Out)
{
    __shared__ alignas(1024) char pool[131072];

    const int tid  = threadIdx.x;
    const int lane = tid & 63;
    const int w    = tid >> 6;
    const int wm   = w >> 2;
    const int wn   = w & 3;
    const int wn1  = wn & 1;
    const int quad = lane >> 4, l15 = lane & 15;

    int m0, n0;
    gemm_remap(blockIdx.y * 8 + blockIdx.x, m0, n0);

    const int scol = ((lane & 7) * 8) ^ ((lane & 32) ? 16 : 0);

    const int rA0 = RA00 + wm * 16384;
    const int rA1 = RA10 + wm * 16384;
    const int rB0 = RB00 + (wn >> 1) * 16384;
    const int rB1 = RB10 + (wn >> 1) * 16384;

    const bf16* Ab = A + (size_t)m0 * ND;
    const bf16* Bb = Wt + (size_t)n0 * ND;

    f32x4 acc[8][4] = {};
    bf16x8 af[8], bfr[8];

    GEMM256_KLOOP(Ab, Bb)

    #pragma unroll
    for (int ni = 0; ni < 4; ++ni) {
        int colg = n0 + wn * 64 + ni * 16 + l15;
        float bn = bias[colg];
        #pragma unroll
        for (int mi = 0; mi < 8; ++mi)
            #pragma unroll
            for (int r = 0; r < 4; ++r) {
                int mg = m0 + wm * 128 + mi * 16 + quad * 4 + r;
                Out[(size_t)mg * ND + colg] = acc[mi][ni][r] + bn;
            }
    }
}

// ---------------------------------------------------------------------------
extern "C" void kernel_launch(void* const* d_in, const int* in_sizes, int n_in,
                              void* d_out, int out_size, void* d_ws, size_t ws_size,
                              hipStream_t stream)
{
    const float* q  = (const float*)d_in[0];
    const float* k  = (const float*)d_in[1];
    const float* v  = (const float*)d_in[2];
    const float* Wq = (const float*)d_in[3];
    const float* bq = (const float*)d_in[4];
    const float* Wk = (const float*)d_in[5];
    const float* bk = (const float*)d_in[6];
    const float* Wv = (const float*)d_in[7];
    const float* bv = (const float*)d_in[8];
    const float* Wo = (const float*)d_in[9];
    const float* bo = (const float*)d_in[10];
    const float* qw = (const float*)d_in[11];
    const float* kw = (const float*)d_in[12];
    float* out = (float*)d_out;

    const size_t nX = (size_t)NB * NS * ND;   // 16,777,216
    const size_t nW = (size_t)ND * ND;        //  4,194,304

    bf16* Xb  = (bf16*)d_ws;
    bf16* Wb  = Xb + 3 * nX;
    bf16* Qn  = Wb + 4 * nW;
    bf16* Kn  = Qn + nX;
    bf16* Vtp = Kn + nX;
    bf16* Ob  = Xb;

    cvt_all<<<32768, 256, 0, stream>>>(q, k, v, Wq, Wk, Wv, Wo, Xb, Wb);

    qkv_gemm<<<dim3(8, 32, 3), dim3(512), 0, stream>>>(
        Xb, Wb, bq, bk, bv, qw, kw, Qn, Kn, Vtp);
    flash_attn<<<dim3(8, 16, 4), dim3(512), 0, stream>>>(Qn, Kn, Vtp, Ob);
    oproj_gemm<<<dim3(8, 32), dim3(512), 0, stream>>>(Ob, Wb + 3 * nW, bo, out);
}

// Round 5
// 712.056 us; speedup vs baseline: 1.4475x; 1.0040x over previous
//
#include <hip/hip_runtime.h>

#define NB 4
#define NS 2048
#define ND 2048
#define NH 16
#define NHD 128

typedef __bf16 bf16;
typedef __attribute__((ext_vector_type(8))) __bf16 bf16x8;
typedef __attribute__((ext_vector_type(4))) __bf16 bf16x4;
typedef __attribute__((ext_vector_type(4))) float f32x4;
typedef __attribute__((ext_vector_type(16))) float f32x16;

#define MFMA(a, b, c) __builtin_amdgcn_mfma_f32_16x16x32_bf16(a, b, c, 0, 0, 0)
#define MFMA32(a, b, c) __builtin_amdgcn_mfma_f32_32x32x16_bf16(a, b, c, 0, 0, 0)

// async global->LDS, 16 B per lane. LDS dest = wave-uniform base + lane*16.
__device__ __forceinline__ void gload16(const bf16* g, bf16* l) {
    __builtin_amdgcn_global_load_lds(
        (const __attribute__((address_space(1))) void*)g,
        (__attribute__((address_space(3))) void*)l, 16, 0, 0);
}

#define BAR() do { asm volatile("" ::: "memory"); __builtin_amdgcn_s_barrier(); \
                   asm volatile("" ::: "memory"); } while (0)
#define VMCNT4() asm volatile("s_waitcnt vmcnt(4)" ::: "memory")
#define VMCNT0() asm volatile("s_waitcnt vmcnt(0)" ::: "memory")

// ---------------------------------------------------------------------------
// 256x256x64 8-phase GEMM machinery (plain-HIP port of the HK cdna4 schedule)
// Swizzle (2-bit involution): byte ^= (row & 12) << 3, i.e. row&4 -> ^32 B,
// row&8 -> ^64 B. Spreads a 64-lane fragment read over all 8 16B-slots of
// the 128 B bank space (8 lanes/slot = conflict-free minimum). Applied as
// linear gload_lds dest + inverse-swizzled global source col + swizzled read.
// ---------------------------------------------------------------------------
enum { RA00 = 0, RA01 = 16384, RA10 = 32768, RA11 = 49152,
       RB00 = 65536, RB01 = 81920, RB10 = 98304, RB11 = 114688 };

// stage one 128x64 half-tile. LDS rows w*16+(lane>>3) (+8 for 2nd chunk);
// source col carries the involution: row&4 == lane&32 -> ^16 elems (in scol),
// 2nd chunk has row&8=8 -> additional ^32 elems.
__device__ __forceinline__ void stage_half(const bf16* gcorner, char* lds_region,
                                           int w, int lane, int scol) {
    const bf16* g = gcorner + (size_t)(w * 16 + (lane >> 3)) * ND;
    gload16(g + scol, (bf16*)(lds_region + w * 2048));
    gload16(g + (size_t)8 * ND + (scol ^ 32), (bf16*)(lds_region + w * 2048 + 1024));
}

__device__ __forceinline__ void lds_loadA(const char* pool, int region, int mi0,
                                          int l15, int quad, bf16x8 (&af)[8]) {
    const int flip = (l15 & 12) << 3;
    #pragma unroll
    for (int mi = 0; mi < 4; ++mi) {
        const int rb = region + ((mi0 + mi) * 16 + l15) * 128;
        #pragma unroll
        for (int kk = 0; kk < 2; ++kk)
            af[mi * 2 + kk] = *reinterpret_cast<const bf16x8*>(
                pool + rb + ((kk * 64 + quad * 16) ^ flip));
    }
}

template <int NI0>
__device__ __forceinline__ void lds_loadB(const char* pool, int region, int wn1,
                                          int l15, int quad, bf16x8 (&bfr)[8]) {
    const int flip = (l15 & 12) << 3;
    #pragma unroll
    for (int ni = 0; ni < 2; ++ni) {
        const int rb = region + (wn1 * 64 + (NI0 + ni) * 16 + l15) * 128;
        #pragma unroll
        for (int kk = 0; kk < 2; ++kk)
            bfr[(NI0 + ni) * 2 + kk] = *reinterpret_cast<const bf16x8*>(
                pool + rb + ((kk * 64 + quad * 16) ^ flip));
    }
}

template <int MI0, int NI0>
__device__ __forceinline__ void mfma_quad(f32x4 (&acc)[8][4], const bf16x8 (&af)[8],
                                          const bf16x8 (&bfr)[8]) {
    __builtin_amdgcn_s_setprio(1);
    #pragma unroll
    for (int mi = 0; mi < 4; ++mi)
        #pragma unroll
        for (int ni = 0; ni < 2; ++ni)
            #pragma unroll
            for (int kk = 0; kk < 2; ++kk)
                acc[MI0 + mi][NI0 + ni] =
                    MFMA(af[mi * 2 + kk], bfr[(NI0 + ni) * 2 + kk], acc[MI0 + mi][NI0 + ni]);
    __builtin_amdgcn_s_setprio(0);
}

#define GEMM256_KLOOP(Ab, Bb)                                                        \
    stage_half(Ab, pool + RA00, w, lane, scol);                                      \
    stage_half(Ab + (size_t)128 * ND, pool + RA01, w, lane, scol);                   \
    stage_half(Bb, pool + RB00, w, lane, scol);                                      \
    stage_half(Bb + (size_t)128 * ND, pool + RB01, w, lane, scol);                   \
    stage_half(Bb + 64, pool + RB10, w, lane, scol);                                 \
    stage_half(Bb + (size_t)128 * ND + 64, pool + RB11, w, lane, scol);              \
    VMCNT4();                                                                        \
    BAR();                                                                           \
    for (int i = 0; i < 16; ++i) {                                                   \
        const int kA = (2 * i + 1) * 64;                                             \
        const int kN = (2 * i + 2) * 64;                                             \
        const int kN3 = (2 * i + 3) * 64;                                            \
        /* P1 */                                                                     \
        lds_loadA(pool, rA0, 0, l15, quad, af);                                      \
        lds_loadB<0>(pool, rB0, wn1, l15, quad, bfr);                                \
        stage_half(Ab + kA, pool + RA10, w, lane, scol);                             \
        BAR(); mfma_quad<0, 0>(acc, af, bfr); BAR();                                 \
        /* P2 */                                                                     \
        lds_loadB<2>(pool, rB0, wn1, l15, quad, bfr);                                \
        stage_half(Ab + (size_t)128 * ND + kA, pool + RA11, w, lane, scol);          \
        BAR(); mfma_quad<0, 2>(acc, af, bfr); BAR();                                 \
        /* P3 */                                                                     \
        lds_loadA(pool, rA0, 4, l15, quad, af);                                      \
        stage_half(Bb + kN, pool + RB00, w, lane, scol);                             \
        BAR(); mfma_quad<4, 0>(acc, af, bfr); BAR();                                 \
        /* P4 */                                                                     \
        stage_half(Bb + (size_t)128 * ND + kN, pool + RB01, w, lane, scol);          \
        VMCNT4();                                                                    \
        BAR(); mfma_quad<4, 2>(acc, af, bfr); BAR();                                 \
        /* P5 */                                                                     \
        lds_loadA(pool, rA1, 0, l15, quad, af);                                      \
        lds_loadB<0>(pool, rB1, wn1, l15, quad, bfr);                                \
        stage_half(Ab + kN, pool + RA00, w, lane, scol);                             \
        BAR(); mfma_quad<0, 0>(acc, af, bfr); BAR();                                 \
        /* P6 */                                                                     \
        lds_loadB<2>(pool, rB1, wn1, l15, quad, bfr);                                \
        stage_half(Ab + (size_t)128 * ND + kN, pool + RA01, w, lane, scol);          \
        BAR(); mfma_quad<0, 2>(acc, af, bfr); BAR();                                 \
        /* P7 */                                                                     \
        lds_loadA(pool, rA1, 4, l15, quad, af);                                      \
        stage_half(Bb + kN3, pool + RB10, w, lane, scol);                            \
        BAR(); mfma_quad<4, 0>(acc, af, bfr); BAR();                                 \
        /* P8 */                                                                     \
        stage_half(Bb + (size_t)128 * ND + kN3, pool + RB11, w, lane, scol);         \
        VMCNT4();                                                                    \
        BAR(); mfma_quad<4, 2>(acc, af, bfr); BAR();                                 \
    }

// ---------------------------------------------------------------------------
// Kernel 0: fused fp32 -> bf16 convert for all 7 tensors (one launch).
// ---------------------------------------------------------------------------
__global__ __launch_bounds__(256) void cvt_all(
    const float* __restrict__ q, const float* __restrict__ k, const float* __restrict__ v,
    const float* __restrict__ Wq, const float* __restrict__ Wk,
    const float* __restrict__ Wv, const float* __restrict__ Wo,
    bf16* __restrict__ Xb, bf16* __restrict__ Wb)
{
    const size_t nX = (size_t)NB * NS * ND;
    const size_t nW = (size_t)ND * ND;
    int bid = blockIdx.x;
    const float* src; bf16* dst;
    if (bid < 24576) {
        int sel = bid >> 13;
        src = (sel == 0) ? q : (sel == 1) ? k : v;
        dst = Xb + (size_t)sel * nX;
        bid &= 8191;
    } else {
        int sel = (bid - 24576) >> 11;
        src = (sel == 0) ? Wq : (sel == 1) ? Wk : (sel == 2) ? Wv : Wo;
        dst = Wb + (size_t)sel * nW;
        bid = (bid - 24576) & 2047;
    }
    size_t i = ((size_t)bid * 256 + threadIdx.x) * 8;
    float4 a = *reinterpret_cast<const float4*>(src + i);
    float4 b = *reinterpret_cast<const float4*>(src + i + 4);
    bf16x8 o;
    o[0] = (bf16)a.x; o[1] = (bf16)a.y; o[2] = (bf16)a.z; o[3] = (bf16)a.w;
    o[4] = (bf16)b.x; o[5] = (bf16)b.y; o[6] = (bf16)b.z; o[7] = (bf16)b.w;
    *reinterpret_cast<bf16x8*>(dst + i) = o;
}

// XCD-chunked remap for the 32m x 8n GEMM grids: hardware flat id f -> tile.
__device__ __forceinline__ void gemm_remap(int flat, int& m0, int& n0) {
    int xcd = flat & 7;
    int idx = flat >> 3;
    m0 = (xcd * 4 + (idx >> 3)) * 256;
    n0 = (idx & 7) * 256;
}

// ---------------------------------------------------------------------------
// Kernel 1: fused QKV projection + bias + per-head RMSNorm (Q,K), V transposed.
// ---------------------------------------------------------------------------
__global__ __launch_bounds__(512, 2) void qkv_gemm(
    const bf16* __restrict__ Xb, const bf16* __restrict__ Wb,
    const float* __restrict__ bq, const float* __restrict__ bk, const float* __restrict__ bv,
    const float* __restrict__ qw, const float* __restrict__ kw,
    bf16* __restrict__ Oq, bf16* __restrict__ Ok, bf16* __restrict__ Ov)
{
    const int mat = blockIdx.z;
    const bf16* X     = Xb + (size_t)mat * (size_t)NB * NS * ND;
    const bf16* W     = Wb + (size_t)mat * ND * ND;
    const float* bias = (mat == 0) ? bq : (mat == 1) ? bk : bv;
    const float* nw   = (mat == 0) ? qw : kw;
    bf16* Out         = (mat == 0) ? Oq : (mat == 1) ? Ok : Ov;

    __shared__ alignas(1024) char pool[131072];
    __shared__ float red[256][4];
    __shared__ float scl[256][2];

    const int tid  = threadIdx.x;
    const int lane = tid & 63;
    const int w    = tid >> 6;
    const int wm   = w >> 2;
    const int wn   = w & 3;
    const int wn1  = wn & 1;
    const int quad = lane >> 4, l15 = lane & 15;

    int m0, n0;
    gemm_remap(blockIdx.y * 8 + blockIdx.x, m0, n0);

    const int scol = ((lane & 7) * 8) ^ ((lane & 32) ? 16 : 0);

    const int rA0 = RA00 + wm * 16384;
    const int rA1 = RA10 + wm * 16384;
    const int rB0 = RB00 + (wn >> 1) * 16384;
    const int rB1 = RB10 + (wn >> 1) * 16384;

    const bf16* Ab = X + (size_t)m0 * ND;
    const bf16* Bb = W + (size_t)n0 * ND;

    f32x4 acc[8][4] = {};
    bf16x8 af[8], bfr[8];

    GEMM256_KLOOP(Ab, Bb)

    #pragma unroll
    for (int ni = 0; ni < 4; ++ni) {
        float bn = bias[n0 + wn * 64 + ni * 16 + l15];
        #pragma unroll
        for (int mi = 0; mi < 8; ++mi)
            #pragma unroll
            for (int r = 0; r < 4; ++r)
                acc[mi][ni][r] += bn;
    }

    if (mat == 2) {
        bf16 (*Ts)[264] = (bf16(*)[264])pool;
        const int bb = m0 >> 11;
        const int s0 = m0 & (NS - 1);
        #pragma unroll
        for (int h2 = 0; h2 < 2; ++h2) {
            __syncthreads();
            if ((wn >> 1) == h2) {
                #pragma unroll
                for (int mi = 0; mi < 8; ++mi)
                    #pragma unroll
                    for (int ni = 0; ni < 4; ++ni) {
                        bf16x4 t;
                        #pragma unroll
                        for (int r = 0; r < 4; ++r) t[r] = (bf16)acc[mi][ni][r];
                        *reinterpret_cast<bf16x4*>(
                            &Ts[wn1 * 64 + ni * 16 + l15][wm * 128 + mi * 16 + quad * 4]) = t;
                    }
            }
            __syncthreads();
            const size_t obase = ((size_t)bb * NH + (n0 >> 7) + h2) * (size_t)NHD * NS;
            #pragma unroll
            for (int it = 0; it < 8; ++it) {
                int d = it * 16 + (tid >> 5);
                int c = (tid & 31) * 8;
                *reinterpret_cast<bf16x8*>(Out + obase + (size_t)d * NS + s0 + c) =
                    *reinterpret_cast<const bf16x8*>(&Ts[d][c]);
            }
        }
        return;
    }

    #pragma unroll
    for (int mi = 0; mi < 8; ++mi) {
        float ss[4];
        #pragma unroll
        for (int r = 0; r < 4; ++r) {
            float s = 0.f;
            #pragma unroll
            for (int ni = 0; ni < 4; ++ni) { float v = acc[mi][ni][r]; s += v * v; }
            ss[r] = s;
        }
        #pragma unroll
        for (int off = 1; off < 16; off <<= 1)
            #pragma unroll
            for (int r = 0; r < 4; ++r)
                ss[r] += __shfl_xor(ss[r], off);
        if (l15 == 0) {
            #pragma unroll
            for (int r = 0; r < 4; ++r)
                red[wm * 128 + mi * 16 + quad * 4 + r][wn] = ss[r];
        }
    }
    __syncthreads();
    {
        int row = tid >> 1, h2 = tid & 1;
        scl[row][h2] = rsqrtf((red[row][2 * h2] + red[row][2 * h2 + 1]) * (1.0f / 128.0f) + 1e-6f);
    }
    __syncthreads();

    const int hh = (n0 >> 7) + (wn >> 1);
    #pragma unroll
    for (int mi = 0; mi < 8; ++mi) {
        #pragma unroll
        for (int r = 0; r < 4; ++r) {
            int row = wm * 128 + mi * 16 + quad * 4 + r;
            int mg  = m0 + row;
            int bb  = mg >> 11;
            int ssi = mg & (NS - 1);
            size_t base = (((size_t)bb * NH + hh) * NS + ssi) * NHD;
            float sc_r = scl[row][wn >> 1];
            #pragma unroll
            for (int ni = 0; ni < 4; ++ni) {
                int col = (wn * 64 + ni * 16 + l15) & 127;
                Out[base + col] = (bf16)(acc[mi][ni][r] * sc_r * nw[col]);
            }
        }
    }
}

// ---------------------------------------------------------------------------
// Kernel 2: flash attention, 8-wave / 32x32-MFMA + XCD-chunked remap
// (unchanged — its swizzle already covers all 8 bank slots).
// ---------------------------------------------------------------------------
__global__ __launch_bounds__(512, 2) void flash_attn(
    const bf16* __restrict__ Q, const bf16* __restrict__ K, const bf16* __restrict__ Vt,
    bf16* __restrict__ O)
{
    __shared__ alignas(1024) char kpool[32768];   // 2 x [64 keys][256 B] swizzled
    __shared__ alignas(1024) char vpool[32768];   // 2 x [128 d][128 B] swizzled
    __shared__ alignas(1024) char ppool[32768];   // 8 waves x [32 q][128 B] swizzled

    const int tid  = threadIdx.x;
    const int lane = tid & 63;
    const int w    = tid >> 6;          // 0..7
    const int l31  = lane & 31;
    const int hi   = lane >> 5;         // 0/1

    const int flat = (blockIdx.z * NH + blockIdx.y) * gridDim.x + blockIdx.x;
    const int qt   = flat >> 6;         // 0..7
    const int bh   = flat & 63;
    const int b    = bh >> 4, h = bh & 15;
    const int q0   = qt * 256;

    const size_t hb = ((size_t)b * NH + h) * (size_t)NS * NHD;
    const bf16* Qh  = Q + hb;
    const bf16* Kh  = K + hb;
    const bf16* Vth = Vt + hb;          // (b,h,d,s)

    bf16x8 qf[8];
    {
        const bf16* qrow = Qh + (size_t)(q0 + w * 32 + l31) * NHD + hi * 8;
        #pragma unroll
        for (int ks = 0; ks < 8; ++ks)
            qf[ks] = *reinterpret_cast<const bf16x8*>(qrow + ks * 16);
    }

    char* Psb = ppool + w * 4096;       // this wave's 32x64 P slab
    const int swz = (l31 & 7) << 4;
    const int qrow_b = l31 * 128;

    f32x16 o0 = {}, o1 = {}, o2 = {}, o3 = {};
    float m_r = -1e30f, l_r = 0.f;
    const float C = 0.12751740f;        // (1/sqrt(128)) * log2(e)

    auto stage_tile = [&](int t, int bufsel) {
        const bf16* Kt  = Kh  + (size_t)(t & 31) * 64 * NHD;
        const bf16* Vtt = Vth + (size_t)(t & 31) * 64;
        char* Kb = kpool + bufsel * 16384;
        char* Vb = vpool + bufsel * 16384;
        #pragma unroll
        for (int j = 0; j < 2; ++j) {
            int c = w * 2 + j;
            int krow  = 4 * c + (lane >> 4);
            int kslot = (lane & 15) ^ (4 * (c & 1) + (lane >> 4));
            gload16(Kt + (size_t)krow * NHD + kslot * 8, (bf16*)(Kb + c * 1024));
            int vrow  = 8 * c + (lane >> 3);
            int vslot = (lane & 7) ^ (lane >> 3);
            gload16(Vtt + (size_t)vrow * NS + vslot * 8, (bf16*)(Vb + c * 1024));
        }
    };

    stage_tile(0, 0);

    const int NT = NS / 64;
    for (int kt = 0; kt < NT; ++kt) {
        const int cur = kt & 1;
        if (kt + 1 < NT) {
            stage_tile(kt + 1, cur ^ 1);
            VMCNT4();
        } else {
            VMCNT0();
        }
        BAR();

        const char* Kb = kpool + cur * 16384;
        const char* Vb = vpool + cur * 16384;

        f32x16 s0 = {}, s1 = {};
        __builtin_amdgcn_s_setprio(1);
        #pragma unroll
        for (int ks = 0; ks < 8; ++ks) {
            const int co = ks * 32 + hi * 16;
            bf16x8 k0 = *reinterpret_cast<const bf16x8*>(
                Kb + l31 * 256 + (co ^ swz));
            bf16x8 k1 = *reinterpret_cast<const bf16x8*>(
                Kb + (32 + l31) * 256 + (co ^ swz));
            s0 = MFMA32(k0, qf[ks], s0);
            s1 = MFMA32(k1, qf[ks], s1);
        }
        __builtin_amdgcn_s_setprio(0);

        float mt = s0[0];
        #pragma unroll
        for (int r = 1; r < 16; ++r) mt = fmaxf(mt, s0[r]);
        #pragma unroll
        for (int r = 0; r < 16; ++r) mt = fmaxf(mt, s1[r]);
        mt = fmaxf(mt, __shfl_xor(mt, 32));

        const bool grow = !__all(mt - m_r <= 64.0f);
        float alpha = 1.f;
        if (grow) {
            float mn = fmaxf(m_r, mt);
            alpha = __builtin_amdgcn_exp2f((m_r - mn) * C);
            m_r = mn;
        }
        const float mC = m_r * C;
        float rs = 0.f;
        #pragma unroll
        for (int r = 0; r < 16; ++r) { s0[r] = __builtin_amdgcn_exp2f(s0[r] * C - mC); rs += s0[r]; }
        #pragma unroll
        for (int r = 0; r < 16; ++r) { s1[r] = __builtin_amdgcn_exp2f(s1[r] * C - mC); rs += s1[r]; }
        rs += __shfl_xor(rs, 32);
        l_r = l_r * alpha + rs;

        #pragma unroll
        for (int g = 0; g < 4; ++g) {
            bf16x4 t0, t1;
            #pragma unroll
            for (int j = 0; j < 4; ++j) {
                t0[j] = (bf16)s0[g * 4 + j];
                t1[j] = (bf16)s1[g * 4 + j];
            }
            *reinterpret_cast<bf16x4*>(Psb + qrow_b + ((g * 16 + hi * 8) ^ swz)) = t0;
            *reinterpret_cast<bf16x4*>(Psb + qrow_b + ((64 + g * 16 + hi * 8) ^ swz)) = t1;
        }

        if (grow) {
            #pragma unroll
            for (int r = 0; r < 16; ++r) {
                float av = __shfl(alpha, (r & 3) + 8 * (r >> 2) + 4 * hi);
                o0[r] *= av; o1[r] *= av; o2[r] *= av; o3[r] *= av;
            }
        }

        __builtin_amdgcn_s_setprio(1);
        #pragma unroll
        for (int ks = 0; ks < 4; ++ks) {
            const int co = ks * 32 + hi * 16;
            bf16x8 pa = *reinterpret_cast<const bf16x8*>(Psb + qrow_b + (co ^ swz));
            bf16x8 v0 = *reinterpret_cast<const bf16x8*>(Vb + l31 * 128 + (co ^ swz));
            bf16x8 v1 = *reinterpret_cast<const bf16x8*>(Vb + (32 + l31) * 128 + (co ^ swz));
            bf16x8 v2 = *reinterpret_cast<const bf16x8*>(Vb + (64 + l31) * 128 + (co ^ swz));
            bf16x8 v3 = *reinterpret_cast<const bf16x8*>(Vb + (96 + l31) * 128 + (co ^ swz));
            o0 = MFMA32(pa, v0, o0);
            o1 = MFMA32(pa, v1, o1);
            o2 = MFMA32(pa, v2, o2);
            o3 = MFMA32(pa, v3, o3);
        }
        __builtin_amdgcn_s_setprio(0);

        BAR();
    }

    #pragma unroll
    for (int r = 0; r < 16; ++r) {
        int qp = (r & 3) + 8 * (r >> 2) + 4 * hi;
        float inv = 1.0f / __shfl(l_r, qp);
        int sg = q0 + w * 32 + qp;
        size_t base = ((size_t)b * NS + sg) * ND + (size_t)h * NHD + l31;
        O[base]      = (bf16)(o0[r] * inv);
        O[base + 32] = (bf16)(o1[r] * inv);
        O[base + 64] = (bf16)(o2[r] * inv);
        O[base + 96] = (bf16)(o3[r] * inv);
    }
}

// ---------------------------------------------------------------------------
// Kernel 3: output projection, 256x256 8-phase + XCD-chunked remap.
// ---------------------------------------------------------------------------
__global__ __launch_bounds__(512, 2) void oproj_gemm(
    const bf16* __restrict__ A, const bf16* __restrict__ Wt,
    const float* __restrict__ bias, float* __restrict__ Out)
{
    __shared__ alignas(1024) char pool[131072];

    const int tid  = threadIdx.x;
    const int lane = tid & 63;
    const int w    = tid >> 6;
    const int wm   = w >> 2;
    const int wn   = w & 3;
    const int wn1  = wn & 1;
    const int quad = lane >> 4, l15 = lane & 15;

    int m0, n0;
    gemm_remap(blockIdx.y * 8 + blockIdx.x, m0, n0);

    const int scol = ((lane & 7) * 8) ^ ((lane & 32) ? 16 : 0);

    const int rA0 = RA00 + wm * 16384;
    const int rA1 = RA10 + wm * 16384;
    const int rB0 = RB00 + (wn >> 1) * 16384;
    const int rB1 = RB10 + (wn >> 1) * 16384;

    const bf16* Ab = A + (size_t)m0 * ND;
    const bf16* Bb = Wt + (size_t)n0 * ND;

    f32x4 acc[8][4] = {};
    bf16x8 af[8], bfr[8];

    GEMM256_KLOOP(Ab, Bb)

    #pragma unroll
    for (int ni = 0; ni < 4; ++ni) {
        int colg = n0 + wn * 64 + ni * 16 + l15;
        float bn = bias[colg];
        #pragma unroll
        for (int mi = 0; mi < 8; ++mi)
            #pragma unroll
            for (int r = 0; r < 4; ++r) {
                int mg = m0 + wm * 128 + mi * 16 + quad * 4 + r;
                Out[(size_t)mg * ND + colg] = acc[mi][ni][r] + bn;
            }
    }
}

// ---------------------------------------------------------------------------
extern "C" void kernel_launch(void* const* d_in, const int* in_sizes, int n_in,
                              void* d_out, int out_size, void* d_ws, size_t ws_size,
                              hipStream_t stream)
{
    const float* q  = (const float*)d_in[0];
    const float* k  = (const float*)d_in[1];
    const float* v  = (const float*)d_in[2];
    const float* Wq = (const float*)d_in[3];
    const float* bq = (const float*)d_in[4];
    const float* Wk = (const float*)d_in[5];
    const float* bk = (const float*)d_in[6];
    const float* Wv = (const float*)d_in[7];
    const float* bv = (const float*)d_in[8];
    const float* Wo = (const float*)d_in[9];
    const float* bo = (const float*)d_in[10];
    const float* qw = (const float*)d_in[11];
    const float* kw = (const float*)d_in[12];
    float* out = (float*)d_out;

    const size_t nX = (size_t)NB * NS * ND;   // 16,777,216
    const size_t nW = (size_t)ND * ND;        //  4,194,304

    bf16* Xb  = (bf16*)d_ws;
    bf16* Wb  = Xb + 3 * nX;
    bf16* Qn  = Wb + 4 * nW;
    bf16* Kn  = Qn + nX;
    bf16* Vtp = Kn + nX;
    bf16* Ob  = Xb;

    cvt_all<<<32768, 256, 0, stream>>>(q, k, v, Wq, Wk, Wv, Wo, Xb, Wb);

    qkv_gemm<<<dim3(8, 32, 3), dim3(512), 0, stream>>>(
        Xb, Wb, bq, bk, bv, qw, kw, Qn, Kn, Vtp);
    flash_attn<<<dim3(8, 16, 4), dim3(512), 0, stream>>>(Qn, Kn, Vtp, Ob);
    oproj_gemm<<<dim3(8, 32), dim3(512), 0, stream>>>(Ob, Wb + 3 * nW, bo, out);
}

// Round 7
// 698.964 us; speedup vs baseline: 1.4746x; 1.0187x over previous
//
#include <hip/hip_runtime.h>

#define NB 4
#define NS 2048
#define ND 2048
#define NH 16
#define NHD 128

typedef __bf16 bf16;
typedef __attribute__((ext_vector_type(8))) __bf16 bf16x8;
typedef __attribute__((ext_vector_type(4))) __bf16 bf16x4;
typedef __attribute__((ext_vector_type(4))) float f32x4;
typedef __attribute__((ext_vector_type(16))) float f32x16;

#define MFMA(a, b, c) __builtin_amdgcn_mfma_f32_16x16x32_bf16(a, b, c, 0, 0, 0)
#define MFMA32(a, b, c) __builtin_amdgcn_mfma_f32_32x32x16_bf16(a, b, c, 0, 0, 0)

// async global->LDS, 16 B per lane. LDS dest = wave-uniform base + lane*16.
__device__ __forceinline__ void gload16(const bf16* g, bf16* l) {
    __builtin_amdgcn_global_load_lds(
        (const __attribute__((address_space(1))) void*)g,
        (__attribute__((address_space(3))) void*)l, 16, 0, 0);
}

#define BAR() do { asm volatile("" ::: "memory"); __builtin_amdgcn_s_barrier(); \
                   asm volatile("" ::: "memory"); } while (0)
#define VMCNT4() asm volatile("s_waitcnt vmcnt(4)" ::: "memory")
#define VMCNT0() asm volatile("s_waitcnt vmcnt(0)" ::: "memory")

// ---------------------------------------------------------------------------
// 256x256x64 8-phase GEMM machinery. ONE barrier per phase. Safety rule:
// passing BAR_p guarantees all waves executed MFMA_{p-1} (so phase p-1 reads
// are drained) and issued phase-p reads. Hence a stage issued BEFORE BAR_p is
// safe only vs reads in phases <= p-2; a stage issued AFTER BAR_p is safe vs
// reads <= p-1. RB00 (read P1/P2, staged P3) and RB10 (read P5/P6, staged P7)
// are distance-1 -> their stages go AFTER the phase barrier. All other stages
// are distance >= 2 and stay before the barrier. vmcnt(4) at P4/P8 + barrier
// carries staged-data visibility (issue order unchanged).
// ---------------------------------------------------------------------------
enum { RA00 = 0, RA01 = 16384, RA10 = 32768, RA11 = 49152,
       RB00 = 65536, RB01 = 81920, RB10 = 98304, RB11 = 114688 };

// stage one 128x64 half-tile. LDS rows w*16+(lane>>3) (+8 for 2nd chunk);
// source col carries the involution: row&4 == lane&32 -> ^16 elems (in scol),
// 2nd chunk has row&8=8 -> additional ^32 elems.
__device__ __forceinline__ void stage_half(const bf16* gcorner, char* lds_region,
                                           int w, int lane, int scol) {
    const bf16* g = gcorner + (size_t)(w * 16 + (lane >> 3)) * ND;
    gload16(g + scol, (bf16*)(lds_region + w * 2048));
    gload16(g + (size_t)8 * ND + (scol ^ 32), (bf16*)(lds_region + w * 2048 + 1024));
}

__device__ __forceinline__ void lds_loadA(const char* pool, int region, int mi0,
                                          int l15, int quad, bf16x8 (&af)[8]) {
    const int flip = (l15 & 12) << 3;
    #pragma unroll
    for (int mi = 0; mi < 4; ++mi) {
        const int rb = region + ((mi0 + mi) * 16 + l15) * 128;
        #pragma unroll
        for (int kk = 0; kk < 2; ++kk)
            af[mi * 2 + kk] = *reinterpret_cast<const bf16x8*>(
                pool + rb + ((kk * 64 + quad * 16) ^ flip));
    }
}

template <int NI0>
__device__ __forceinline__ void lds_loadB(const char* pool, int region, int wn1,
                                          int l15, int quad, bf16x8 (&bfr)[8]) {
    const int flip = (l15 & 12) << 3;
    #pragma unroll
    for (int ni = 0; ni < 2; ++ni) {
        const int rb = region + (wn1 * 64 + (NI0 + ni) * 16 + l15) * 128;
        #pragma unroll
        for (int kk = 0; kk < 2; ++kk)
            bfr[(NI0 + ni) * 2 + kk] = *reinterpret_cast<const bf16x8*>(
                pool + rb + ((kk * 64 + quad * 16) ^ flip));
    }
}

template <int MI0, int NI0>
__device__ __forceinline__ void mfma_quad(f32x4 (&acc)[8][4], const bf16x8 (&af)[8],
                                          const bf16x8 (&bfr)[8]) {
    __builtin_amdgcn_s_setprio(1);
    #pragma unroll
    for (int mi = 0; mi < 4; ++mi)
        #pragma unroll
        for (int ni = 0; ni < 2; ++ni)
            #pragma unroll
            for (int kk = 0; kk < 2; ++kk)
                acc[MI0 + mi][NI0 + ni] =
                    MFMA(af[mi * 2 + kk], bfr[(NI0 + ni) * 2 + kk], acc[MI0 + mi][NI0 + ni]);
    __builtin_amdgcn_s_setprio(0);
}

#define GEMM256_KLOOP(Ab, Bb)                                                        \
    stage_half(Ab, pool + RA00, w, lane, scol);                                      \
    stage_half(Ab + (size_t)128 * ND, pool + RA01, w, lane, scol);                   \
    stage_half(Bb, pool + RB00, w, lane, scol);                                      \
    stage_half(Bb + (size_t)128 * ND, pool + RB01, w, lane, scol);                   \
    stage_half(Bb + 64, pool + RB10, w, lane, scol);                                 \
    stage_half(Bb + (size_t)128 * ND + 64, pool + RB11, w, lane, scol);              \
    VMCNT4();                                                                        \
    BAR();                                                                           \
    for (int i = 0; i < 16; ++i) {                                                   \
        const int kA = (2 * i + 1) * 64;                                             \
        const int kN = (2 * i + 2) * 64;                                             \
        const int kN3 = (2 * i + 3) * 64;                                            \
        /* P1: stage RA10 (read P5/P7 prev, dist>=2 -> before BAR) */                \
        lds_loadA(pool, rA0, 0, l15, quad, af);                                      \
        lds_loadB<0>(pool, rB0, wn1, l15, quad, bfr);                                \
        stage_half(Ab + kA, pool + RA10, w, lane, scol);                             \
        BAR(); mfma_quad<0, 0>(acc, af, bfr);                                        \
        /* P2: stage RA11 (read P5/P7 prev, dist>=2) */                              \
        lds_loadB<2>(pool, rB0, wn1, l15, quad, bfr);                                \
        stage_half(Ab + (size_t)128 * ND + kA, pool + RA11, w, lane, scol);          \
        BAR(); mfma_quad<0, 2>(acc, af, bfr);                                        \
        /* P3: stage RB00 (read P1/P2, dist 1 -> AFTER BAR) */                       \
        lds_loadA(pool, rA0, 4, l15, quad, af);                                      \
        BAR();                                                                       \
        stage_half(Bb + kN, pool + RB00, w, lane, scol);                             \
        mfma_quad<4, 0>(acc, af, bfr);                                               \
        /* P4: stage RB01 (read P1/P2, dist 2 after P3 BAR) */                       \
        stage_half(Bb + (size_t)128 * ND + kN, pool + RB01, w, lane, scol);          \
        VMCNT4();                                                                    \
        BAR(); mfma_quad<4, 2>(acc, af, bfr);                                        \
        /* P5: stage RA00 (read P1/P3, dist>=2) */                                   \
        lds_loadA(pool, rA1, 0, l15, quad, af);                                      \
        lds_loadB<0>(pool, rB1, wn1, l15, quad, bfr);                                \
        stage_half(Ab + kN, pool + RA00, w, lane, scol);                             \
        BAR(); mfma_quad<0, 0>(acc, af, bfr);                                        \
        /* P6: stage RA01 (read P1/P3, dist>=2) */                                   \
        lds_loadB<2>(pool, rB1, wn1, l15, quad, bfr);                                \
        stage_half(Ab + (size_t)128 * ND + kN, pool + RA01, w, lane, scol);          \
        BAR(); mfma_quad<0, 2>(acc, af, bfr);                                        \
        /* P7: stage RB10 (read P5/P6, dist 1 -> AFTER BAR) */                       \
        lds_loadA(pool, rA1, 4, l15, quad, af);                                      \
        BAR();                                                                       \
        stage_half(Bb + kN3, pool + RB10, w, lane, scol);                            \
        mfma_quad<4, 0>(acc, af, bfr);                                               \
        /* P8: stage RB11 (read P5/P6, dist 2 after P7 BAR) */                       \
        stage_half(Bb + (size_t)128 * ND + kN3, pool + RB11, w, lane, scol);         \
        VMCNT4();                                                                    \
        BAR(); mfma_quad<4, 2>(acc, af, bfr);                                        \
    }

// ---------------------------------------------------------------------------
// Kernel 0: fused fp32 -> bf16 convert for all 7 tensors (one launch).
// ---------------------------------------------------------------------------
__global__ __launch_bounds__(256) void cvt_all(
    const float* __restrict__ q, const float* __restrict__ k, const float* __restrict__ v,
    const float* __restrict__ Wq, const float* __restrict__ Wk,
    const float* __restrict__ Wv, const float* __restrict__ Wo,
    bf16* __restrict__ Xb, bf16* __restrict__ Wb)
{
    const size_t nX = (size_t)NB * NS * ND;
    const size_t nW = (size_t)ND * ND;
    int bid = blockIdx.x;
    const float* src; bf16* dst;
    if (bid < 24576) {
        int sel = bid >> 13;
        src = (sel == 0) ? q : (sel == 1) ? k : v;
        dst = Xb + (size_t)sel * nX;
        bid &= 8191;
    } else {
        int sel = (bid - 24576) >> 11;
        src = (sel == 0) ? Wq : (sel == 1) ? Wk : (sel == 2) ? Wv : Wo;
        dst = Wb + (size_t)sel * nW;
        bid = (bid - 24576) & 2047;
    }
    size_t i = ((size_t)bid * 256 + threadIdx.x) * 8;
    float4 a = *reinterpret_cast<const float4*>(src + i);
    float4 b = *reinterpret_cast<const float4*>(src + i + 4);
    bf16x8 o;
    o[0] = (bf16)a.x; o[1] = (bf16)a.y; o[2] = (bf16)a.z; o[3] = (bf16)a.w;
    o[4] = (bf16)b.x; o[5] = (bf16)b.y; o[6] = (bf16)b.z; o[7] = (bf16)b.w;
    *reinterpret_cast<bf16x8*>(dst + i) = o;
}

// XCD-chunked remap for the 32m x 8n GEMM grids: hardware flat id f -> tile.
__device__ __forceinline__ void gemm_remap(int flat, int& m0, int& n0) {
    int xcd = flat & 7;
    int idx = flat >> 3;
    m0 = (xcd * 4 + (idx >> 3)) * 256;
    n0 = (idx & 7) * 256;
}

// ---------------------------------------------------------------------------
// Kernel 1: fused QKV projection + bias + per-head RMSNorm (Q,K), V transposed.
// ---------------------------------------------------------------------------
__global__ __launch_bounds__(512, 2) void qkv_gemm(
    const bf16* __restrict__ Xb, const bf16* __restrict__ Wb,
    const float* __restrict__ bq, const float* __restrict__ bk, const float* __restrict__ bv,
    const float* __restrict__ qw, const float* __restrict__ kw,
    bf16* __restrict__ Oq, bf16* __restrict__ Ok, bf16* __restrict__ Ov)
{
    const int mat = blockIdx.z;
    const bf16* X     = Xb + (size_t)mat * (size_t)NB * NS * ND;
    const bf16* W     = Wb + (size_t)mat * ND * ND;
    const float* bias = (mat == 0) ? bq : (mat == 1) ? bk : bv;
    const float* nw   = (mat == 0) ? qw : kw;
    bf16* Out         = (mat == 0) ? Oq : (mat == 1) ? Ok : Ov;

    __shared__ alignas(1024) char pool[131072];
    __shared__ float red[256][4];
    __shared__ float scl[256][2];

    const int tid  = threadIdx.x;
    const int lane = tid & 63;
    const int w    = tid >> 6;
    const int wm   = w >> 2;
    const int wn   = w & 3;
    const int wn1  = wn & 1;
    const int quad = lane >> 4, l15 = lane & 15;

    int m0, n0;
    gemm_remap(blockIdx.y * 8 + blockIdx.x, m0, n0);

    const int scol = ((lane & 7) * 8) ^ ((lane & 32) ? 16 : 0);

    const int rA0 = RA00 + wm * 16384;
    const int rA1 = RA10 + wm * 16384;
    const int rB0 = RB00 + (wn >> 1) * 16384;
    const int rB1 = RB10 + (wn >> 1) * 16384;

    const bf16* Ab = X + (size_t)m0 * ND;
    const bf16* Bb = W + (size_t)n0 * ND;

    f32x4 acc[8][4] = {};
    bf16x8 af[8], bfr[8];

    GEMM256_KLOOP(Ab, Bb)

    #pragma unroll
    for (int ni = 0; ni < 4; ++ni) {
        float bn = bias[n0 + wn * 64 + ni * 16 + l15];
        #pragma unroll
        for (int mi = 0; mi < 8; ++mi)
            #pragma unroll
            for (int r = 0; r < 4; ++r)
                acc[mi][ni][r] += bn;
    }

    if (mat == 2) {
        bf16 (*Ts)[264] = (bf16(*)[264])pool;
        const int bb = m0 >> 11;
        const int s0 = m0 & (NS - 1);
        #pragma unroll
        for (int h2 = 0; h2 < 2; ++h2) {
            __syncthreads();               // drains tail gload_lds before pool reuse
            if ((wn >> 1) == h2) {
                #pragma unroll
                for (int mi = 0; mi < 8; ++mi)
                    #pragma unroll
                    for (int ni = 0; ni < 4; ++ni) {
                        bf16x4 t;
                        #pragma unroll
                        for (int r = 0; r < 4; ++r) t[r] = (bf16)acc[mi][ni][r];
                        *reinterpret_cast<bf16x4*>(
                            &Ts[wn1 * 64 + ni * 16 + l15][wm * 128 + mi * 16 + quad * 4]) = t;
                    }
            }
            __syncthreads();
            const size_t obase = ((size_t)bb * NH + (n0 >> 7) + h2) * (size_t)NHD * NS;
            #pragma unroll
            for (int it = 0; it < 8; ++it) {
                int d = it * 16 + (tid >> 5);
                int c = (tid & 31) * 8;
                *reinterpret_cast<bf16x8*>(Out + obase + (size_t)d * NS + s0 + c) =
                    *reinterpret_cast<const bf16x8*>(&Ts[d][c]);
            }
        }
        return;
    }

    #pragma unroll
    for (int mi = 0; mi < 8; ++mi) {
        float ss[4];
        #pragma unroll
        for (int r = 0; r < 4; ++r) {
            float s = 0.f;
            #pragma unroll
            for (int ni = 0; ni < 4; ++ni) { float v = acc[mi][ni][r]; s += v * v; }
            ss[r] = s;
        }
        #pragma unroll
        for (int off = 1; off < 16; off <<= 1)
            #pragma unroll
            for (int r = 0; r < 4; ++r)
                ss[r] += __shfl_xor(ss[r], off);
        if (l15 == 0) {
            #pragma unroll
            for (int r = 0; r < 4; ++r)
                red[wm * 128 + mi * 16 + quad * 4 + r][wn] = ss[r];
        }
    }
    __syncthreads();
    {
        int row = tid >> 1, h2 = tid & 1;
        scl[row][h2] = rsqrtf((red[row][2 * h2] + red[row][2 * h2 + 1]) * (1.0f / 128.0f) + 1e-6f);
    }
    __syncthreads();

    const int hh = (n0 >> 7) + (wn >> 1);
    #pragma unroll
    for (int mi = 0; mi < 8; ++mi) {
        #pragma unroll
        for (int r = 0; r < 4; ++r) {
            int row = wm * 128 + mi * 16 + quad * 4 + r;
            int mg  = m0 + row;
            int bb  = mg >> 11;
            int ssi = mg & (NS - 1);
            size_t base = (((size_t)bb * NH + hh) * NS + ssi) * NHD;
            float sc_r = scl[row][wn >> 1];
            #pragma unroll
            for (int ni = 0; ni < 4; ++ni) {
                int col = (wn * 64 + ni * 16 + l15) & 127;
                Out[base + col] = (bf16)(acc[mi][ni][r] * sc_r * nw[col]);
            }
        }
    }
}

// ---------------------------------------------------------------------------
// Kernel 2: flash attention, 8-wave / 32x32-MFMA + XCD-chunked remap
// (unchanged — its double-buffer reuse distance is 1, both barriers needed).
// ---------------------------------------------------------------------------
__global__ __launch_bounds__(512, 2) void flash_attn(
    const bf16* __restrict__ Q, const bf16* __restrict__ K, const bf16* __restrict__ Vt,
    bf16* __restrict__ O)
{
    __shared__ alignas(1024) char kpool[32768];   // 2 x [64 keys][256 B] swizzled
    __shared__ alignas(1024) char vpool[32768];   // 2 x [128 d][128 B] swizzled
    __shared__ alignas(1024) char ppool[32768];   // 8 waves x [32 q][128 B] swizzled

    const int tid  = threadIdx.x;
    const int lane = tid & 63;
    const int w    = tid >> 6;          // 0..7
    const int l31  = lane & 31;
    const int hi   = lane >> 5;         // 0/1

    const int flat = (blockIdx.z * NH + blockIdx.y) * gridDim.x + blockIdx.x;
    const int qt   = flat >> 6;         // 0..7
    const int bh   = flat & 63;
    const int b    = bh >> 4, h = bh & 15;
    const int q0   = qt * 256;

    const size_t hb = ((size_t)b * NH + h) * (size_t)NS * NHD;
    const bf16* Qh  = Q + hb;
    const bf16* Kh  = K + hb;
    const bf16* Vth = Vt + hb;          // (b,h,d,s)

    bf16x8 qf[8];
    {
        const bf16* qrow = Qh + (size_t)(q0 + w * 32 + l31) * NHD + hi * 8;
        #pragma unroll
        for (int ks = 0; ks < 8; ++ks)
            qf[ks] = *reinterpret_cast<const bf16x8*>(qrow + ks * 16);
    }

    char* Psb = ppool + w * 4096;       // this wave's 32x64 P slab
    const int swz = (l31 & 7) << 4;
    const int qrow_b = l31 * 128;

    f32x16 o0 = {}, o1 = {}, o2 = {}, o3 = {};
    float m_r = -1e30f, l_r = 0.f;
    const float C = 0.12751740f;        // (1/sqrt(128)) * log2(e)

    auto stage_tile = [&](int t, int bufsel) {
        const bf16* Kt  = Kh  + (size_t)(t & 31) * 64 * NHD;
        const bf16* Vtt = Vth + (size_t)(t & 31) * 64;
        char* Kb = kpool + bufsel * 16384;
        char* Vb = vpool + bufsel * 16384;
        #pragma unroll
        for (int j = 0; j < 2; ++j) {
            int c = w * 2 + j;
            int krow  = 4 * c + (lane >> 4);
            int kslot = (lane & 15) ^ (4 * (c & 1) + (lane >> 4));
            gload16(Kt + (size_t)krow * NHD + kslot * 8, (bf16*)(Kb + c * 1024));
            int vrow  = 8 * c + (lane >> 3);
            int vslot = (lane & 7) ^ (lane >> 3);
            gload16(Vtt + (size_t)vrow * NS + vslot * 8, (bf16*)(Vb + c * 1024));
        }
    };

    stage_tile(0, 0);

    const int NT = NS / 64;
    for (int kt = 0; kt < NT; ++kt) {
        const int cur = kt & 1;
        if (kt + 1 < NT) {
            stage_tile(kt + 1, cur ^ 1);
            VMCNT4();
        } else {
            VMCNT0();
        }
        BAR();

        const char* Kb = kpool + cur * 16384;
        const char* Vb = vpool + cur * 16384;

        f32x16 s0 = {}, s1 = {};
        __builtin_amdgcn_s_setprio(1);
        #pragma unroll
        for (int ks = 0; ks < 8; ++ks) {
            const int co = ks * 32 + hi * 16;
            bf16x8 k0 = *reinterpret_cast<const bf16x8*>(
                Kb + l31 * 256 + (co ^ swz));
            bf16x8 k1 = *reinterpret_cast<const bf16x8*>(
                Kb + (32 + l31) * 256 + (co ^ swz));
            s0 = MFMA32(k0, qf[ks], s0);
            s1 = MFMA32(k1, qf[ks], s1);
        }
        __builtin_amdgcn_s_setprio(0);

        float mt = s0[0];
        #pragma unroll
        for (int r = 1; r < 16; ++r) mt = fmaxf(mt, s0[r]);
        #pragma unroll
        for (int r = 0; r < 16; ++r) mt = fmaxf(mt, s1[r]);
        mt = fmaxf(mt, __shfl_xor(mt, 32));

        const bool grow = !__all(mt - m_r <= 64.0f);
        float alpha = 1.f;
        if (grow) {
            float mn = fmaxf(m_r, mt);
            alpha = __builtin_amdgcn_exp2f((m_r - mn) * C);
            m_r = mn;
        }
        const float mC = m_r * C;
        float rs = 0.f;
        #pragma unroll
        for (int r = 0; r < 16; ++r) { s0[r] = __builtin_amdgcn_exp2f(s0[r] * C - mC); rs += s0[r]; }
        #pragma unroll
        for (int r = 0; r < 16; ++r) { s1[r] = __builtin_amdgcn_exp2f(s1[r] * C - mC); rs += s1[r]; }
        rs += __shfl_xor(rs, 32);
        l_r = l_r * alpha + rs;

        #pragma unroll
        for (int g = 0; g < 4; ++g) {
            bf16x4 t0, t1;
            #pragma unroll
            for (int j = 0; j < 4; ++j) {
                t0[j] = (bf16)s0[g * 4 + j];
                t1[j] = (bf16)s1[g * 4 + j];
            }
            *reinterpret_cast<bf16x4*>(Psb + qrow_b + ((g * 16 + hi * 8) ^ swz)) = t0;
            *reinterpret_cast<bf16x4*>(Psb + qrow_b + ((64 + g * 16 + hi * 8) ^ swz)) = t1;
        }

        if (grow) {
            #pragma unroll
            for (int r = 0; r < 16; ++r) {
                float av = __shfl(alpha, (r & 3) + 8 * (r >> 2) + 4 * hi);
                o0[r] *= av; o1[r] *= av; o2[r] *= av; o3[r] *= av;
            }
        }

        __builtin_amdgcn_s_setprio(1);
        #pragma unroll
        for (int ks = 0; ks < 4; ++ks) {
            const int co = ks * 32 + hi * 16;
            bf16x8 pa = *reinterpret_cast<const bf16x8*>(Psb + qrow_b + (co ^ swz));
            bf16x8 v0 = *reinterpret_cast<const bf16x8*>(Vb + l31 * 128 + (co ^ swz));
            bf16x8 v1 = *reinterpret_cast<const bf16x8*>(Vb + (32 + l31) * 128 + (co ^ swz));
            bf16x8 v2 = *reinterpret_cast<const bf16x8*>(Vb + (64 + l31) * 128 + (co ^ swz));
            bf16x8 v3 = *reinterpret_cast<const bf16x8*>(Vb + (96 + l31) * 128 + (co ^ swz));
            o0 = MFMA32(pa, v0, o0);
            o1 = MFMA32(pa, v1, o1);
            o2 = MFMA32(pa, v2, o2);
            o3 = MFMA32(pa, v3, o3);
        }
        __builtin_amdgcn_s_setprio(0);

        BAR();
    }

    #pragma unroll
    for (int r = 0; r < 16; ++r) {
        int qp = (r & 3) + 8 * (r >> 2) + 4 * hi;
        float inv = 1.0f / __shfl(l_r, qp);
        int sg = q0 + w * 32 + qp;
        size_t base = ((size_t)b * NS + sg) * ND + (size_t)h * NHD + l31;
        O[base]      = (bf16)(o0[r] * inv);
        O[base + 32] = (bf16)(o1[r] * inv);
        O[base + 64] = (bf16)(o2[r] * inv);
        O[base + 96] = (bf16)(o3[r] * inv);
    }
}

// ---------------------------------------------------------------------------
// Kernel 3: output projection, 256x256 8-phase + XCD-chunked remap.
// ---------------------------------------------------------------------------
__global__ __launch_bounds__(512, 2) void oproj_gemm(
    const bf16* __restrict__ A, const bf16* __restrict__ Wt,
    const float* __restrict__ bias, float* __restrict__ Out)
{
    __shared__ alignas(1024) char pool[131072];

    const int tid  = threadIdx.x;
    const int lane = tid & 63;
    const int w    = tid >> 6;
    const int wm   = w >> 2;
    const int wn   = w & 3;
    const int wn1  = wn & 1;
    const int quad = lane >> 4, l15 = lane & 15;

    int m0, n0;
    gemm_remap(blockIdx.y * 8 + blockIdx.x, m0, n0);

    const int scol = ((lane & 7) * 8) ^ ((lane & 32) ? 16 : 0);

    const int rA0 = RA00 + wm * 16384;
    const int rA1 = RA10 + wm * 16384;
    const int rB0 = RB00 + (wn >> 1) * 16384;
    const int rB1 = RB10 + (wn >> 1) * 16384;

    const bf16* Ab = A + (size_t)m0 * ND;
    const bf16* Bb = Wt + (size_t)n0 * ND;

    f32x4 acc[8][4] = {};
    bf16x8 af[8], bfr[8];

    GEMM256_KLOOP(Ab, Bb)

    #pragma unroll
    for (int ni = 0; ni < 4; ++ni) {
        int colg = n0 + wn * 64 + ni * 16 + l15;
        float bn = bias[colg];
        #pragma unroll
        for (int mi = 0; mi < 8; ++mi)
            #pragma unroll
            for (int r = 0; r < 4; ++r) {
                int mg = m0 + wm * 128 + mi * 16 + quad * 4 + r;
                Out[(size_t)mg * ND + colg] = acc[mi][ni][r] + bn;
            }
    }
}

// ---------------------------------------------------------------------------
extern "C" void kernel_launch(void* const* d_in, const int* in_sizes, int n_in,
                              void* d_out, int out_size, void* d_ws, size_t ws_size,
                              hipStream_t stream)
{
    const float* q  = (const float*)d_in[0];
    const float* k  = (const float*)d_in[1];
    const float* v  = (const float*)d_in[2];
    const float* Wq = (const float*)d_in[3];
    const float* bq = (const float*)d_in[4];
    const float* Wk = (const float*)d_in[5];
    const float* bk = (const float*)d_in[6];
    const float* Wv = (const float*)d_in[7];
    const float* bv = (const float*)d_in[8];
    const float* Wo = (const float*)d_in[9];
    const float* bo = (const float*)d_in[10];
    const float* qw = (const float*)d_in[11];
    const float* kw = (const float*)d_in[12];
    float* out = (float*)d_out;

    const size_t nX = (size_t)NB * NS * ND;   // 16,777,216
    const size_t nW = (size_t)ND * ND;        //  4,194,304

    bf16* Xb  = (bf16*)d_ws;
    bf16* Wb  = Xb + 3 * nX;
    bf16* Qn  = Wb + 4 * nW;
    bf16* Kn  = Qn + nX;
    bf16* Vtp = Kn + nX;
    bf16* Ob  = Xb;

    cvt_all<<<32768, 256, 0, stream>>>(q, k, v, Wq, Wk, Wv, Wo, Xb, Wb);

    qkv_gemm<<<dim3(8, 32, 3), dim3(512), 0, stream>>>(
        Xb, Wb, bq, bk, bv, qw, kw, Qn, Kn, Vtp);
    flash_attn<<<dim3(8, 16, 4), dim3(512), 0, stream>>>(Qn, Kn, Vtp, Ob);
    oproj_gemm<<<dim3(8, 32), dim3(512), 0, stream>>>(Ob, Wb + 3 * nW, bo, out);
}